// Round 1
// baseline (628.891 us; speedup 1.0000x reference)
//
#include <hip/hip_runtime.h>

#define EPSF 1e-8f

constexpr int NI = 48, NC = 48, S = 36, W = 32, D = 1024, NB = 64;
constexpr int CHUNK = 128, NCH = D / CHUNK;   // 8 chunks
constexpr int CST = CHUNK + 1;                // 129: LDS row stride (conflict-free)

// ---------------- prep: fold conv/MeanOut/weight-norm-linear into cv[64], bconst ----------------
__global__ __launch_bounds__(256) void prep_kernel(
    const float* __restrict__ convW, const float* __restrict__ convB,
    const float* __restrict__ Wm, const float* __restrict__ bm,
    const float* __restrict__ V, const float* __restrict__ g,
    const float* __restrict__ bo, float* __restrict__ ws) {
  __shared__ float wn[256];
  __shared__ float wv[64];
  __shared__ float vscale;
  const int t = threadIdx.x;
  if (t == 0) {
    float s = 0.f;
    for (int h = 0; h < 256; ++h) s += V[h] * V[h];
    vscale = g[0] / sqrtf(s);
  }
  __syncthreads();
  if (t < 256) wn[t] = V[t] * vscale;
  __syncthreads();
  if (t < 64) {
    float acc = 0.f;
    for (int h = 0; h < 256; ++h)
      acc += 0.5f * (Wm[t * 512 + 2 * h] + Wm[t * 512 + 2 * h + 1]) * wn[h];
    wv[t] = acc;
  }
  __syncthreads();
  if (t < 64) {
    float acc = 0.f;
    for (int m = 0; m < 64; ++m) {
      float ce = 0.f;
      for (int k = 0; k < 8; ++k) ce += convW[k * 4096 + t * 64 + m];
      acc += 0.125f * ce * wv[m];
    }
    ws[t] = acc;  // cv[n]
  }
  if (t == 0) {
    float bh = 0.f;
    for (int h = 0; h < 256; ++h) bh += 0.5f * (bm[2 * h] + bm[2 * h + 1]) * wn[h];
    float bc = 0.f;
    for (int m = 0; m < 64; ++m) bc += convB[m] * wv[m];
    ws[64] = bh + bc + bo[0];  // bconst
  }
}

// ---------------- main: one block per (caption, image) pair ----------------
__global__ __launch_bounds__(256, 2) void i2t_kernel(
    const float* __restrict__ images, const float* __restrict__ captions,
    const float* __restrict__ delt,
    const float* __restrict__ W1, const float* __restrict__ b1,
    const float* __restrict__ W2, const float* __restrict__ b2,
    const float* __restrict__ ws, float* __restrict__ out) {
  __shared__ union {
    struct { float cap[W][CST]; float img[S][CST]; } st;   // 35.1 KB staging
    struct { float w1[64][65]; float w2[64][65]; } wm;     // W1/W2 (phase D)
  } uS;
  __shared__ union {
    float lpart[4][W][S];                                  // pass-1 wave partials
    struct { float f1[S][65]; float f2[S][65]; } ff;       // phase D outputs
  } u2;
  __shared__ union {
    struct { float La[W][S + 1]; float attn[S][W + 1]; } aa;
    float G[S][S + 1];                                     // phase E (after attn dead)
  } u3;
  __shared__ float simm[S][NB + 1];
  __shared__ float wrcp[W];
  __shared__ float sDelt[NB], sB1[NB], sB2[NB], sCv[NB];
  __shared__ float sSimcv[S], sRed[S];
  __shared__ float sBconst;

  const int t = threadIdx.x;
  const int bid = blockIdx.x;
  // XCD-tiled (c,i): each XCD gets a 12c x 24i tile (~5 MB working set)
  const int xcd = bid & 7, l = bid >> 3;
  const int ci = (xcd >> 1) * 12 + (l % 12);
  const int ii = (xcd & 1) * 24 + (l / 12);

  const float* cap = captions + ci * (W * D);
  const float* img = images + ii * (S * D);

  if (t < NB) { sDelt[t] = delt[t]; sB1[t] = b1[t]; sB2[t] = b2[t]; sCv[t] = ws[t]; }
  if (t == 0) sBconst = ws[64];

  // ---- pass 1: L[w][s] = sum_d cap[w,d] * img[s,d]
  const int lane = t & 63, wid = t >> 6;
  const int wi = lane & 15, si = lane >> 4;  // 2w x 9s tile per lane
  float acc[2][9];
#pragma unroll
  for (int k = 0; k < 2; ++k)
#pragma unroll
    for (int j = 0; j < 9; ++j) acc[k][j] = 0.f;

  for (int ch = 0; ch < NCH; ++ch) {
    const int d0 = ch * CHUNK;
    for (int q = t; q < (W + S) * (CHUNK / 4); q += 256) {
      if (q < W * (CHUNK / 4)) {
        const int row = q >> 5, c4 = q & 31;
        float4 v = *reinterpret_cast<const float4*>(cap + row * D + d0 + 4 * c4);
        float* p = &uS.st.cap[row][4 * c4];
        p[0] = v.x; p[1] = v.y; p[2] = v.z; p[3] = v.w;
      } else {
        const int qq = q - W * (CHUNK / 4);
        const int row = qq >> 5, c4 = qq & 31;
        float4 v = *reinterpret_cast<const float4*>(img + row * D + d0 + 4 * c4);
        float* p = &uS.st.img[row][4 * c4];
        p[0] = v.x; p[1] = v.y; p[2] = v.z; p[3] = v.w;
      }
    }
    __syncthreads();
    const int db = 32 * wid;  // wave-split K within chunk
#pragma unroll 4
    for (int dd = 0; dd < 32; ++dd) {
      const int d = db + dd;
      const float c0 = uS.st.cap[2 * wi][d];
      const float c1 = uS.st.cap[2 * wi + 1][d];
#pragma unroll
      for (int j = 0; j < 9; ++j) {
        const float im = uS.st.img[9 * si + j][d];
        acc[0][j] += c0 * im;
        acc[1][j] += c1 * im;
      }
    }
    __syncthreads();
  }
#pragma unroll
  for (int k = 0; k < 2; ++k)
#pragma unroll
    for (int j = 0; j < 9; ++j)
      u2.lpart[wid][2 * wi + k][9 * si + j] = acc[k][j];
  __syncthreads();

  // reduce wave partials + leaky_relu
  {
    const float* lp = &u2.lpart[0][0][0];
    for (int e = t; e < W * S; e += 256) {
      float x = lp[e] + lp[e + 1152] + lp[e + 2304] + lp[e + 3456];
      x = x > 0.f ? x : 0.1f * x;
      u3.aa.La[e / S][e % S] = x;
    }
  }
  __syncthreads();
  // per-word inverse l2 norm over regions
  if (t < W) {
    float s = 0.f;
    for (int ss = 0; ss < S; ++ss) { const float v = u3.aa.La[t][ss]; s += v * v; }
    wrcp[t] = 1.f / (sqrtf(s) + EPSF);
  }
  __syncthreads();
  // softmax over words (lambda=9) per region
  if (t < S) {
    float m = -1e30f;
    for (int w = 0; w < W; ++w) m = fmaxf(m, 9.f * u3.aa.La[w][t] * wrcp[w]);
    float sum = 0.f;
    for (int w = 0; w < W; ++w) {
      const float e = expf(9.f * u3.aa.La[w][t] * wrcp[w] - m);
      u3.aa.attn[t][w] = e;
      sum += e;
    }
    const float r = 1.f / sum;
    for (int w = 0; w < W; ++w) u3.aa.attn[t][w] *= r;
  }
  __syncthreads();

  // ---- pass 2: ctx on the fly -> blockwise cosine sim[s][n]
  for (int ch = 0; ch < NCH; ++ch) {
    const int d0 = ch * CHUNK;
    for (int q = t; q < (W + S) * (CHUNK / 4); q += 256) {
      if (q < W * (CHUNK / 4)) {
        const int row = q >> 5, c4 = q & 31;
        float4 v = *reinterpret_cast<const float4*>(cap + row * D + d0 + 4 * c4);
        float* p = &uS.st.cap[row][4 * c4];
        p[0] = v.x; p[1] = v.y; p[2] = v.z; p[3] = v.w;
      } else {
        const int qq = q - W * (CHUNK / 4);
        const int row = qq >> 5, c4 = qq & 31;
        float4 v = *reinterpret_cast<const float4*>(img + row * D + d0 + 4 * c4);
        float* p = &uS.st.img[row][4 * c4];
        p[0] = v.x; p[1] = v.y; p[2] = v.z; p[3] = v.w;
      }
    }
    __syncthreads();
    for (int u = t; u < 8 * S; u += 256) {   // unit = nb*36 + s
      const int s = u % S;
      const int nb = u / S;
      const int dbase = nb * 16;
      float ctx[16];
#pragma unroll
      for (int j = 0; j < 16; ++j) ctx[j] = 0.f;
      for (int w = 0; w < W; ++w) {
        const float aw = u3.aa.attn[s][w];
#pragma unroll
        for (int j = 0; j < 16; ++j) ctx[j] += aw * uS.st.cap[w][dbase + j];
      }
      float dt = 0.f, dc = 0.f, dq = 0.f;
#pragma unroll
      for (int j = 0; j < 16; ++j) {
        const float qv = uS.st.img[s][dbase + j];
        dt += qv * ctx[j];
        dc += ctx[j] * ctx[j];
        dq += qv * qv;
      }
      const int n = ch * 8 + nb;
      const float nrm = sqrtf(dq) * sqrtf(dc);
      simm[s][n] = dt / fmaxf(nrm, EPSF) * sDelt[n];
    }
    __syncthreads();
  }

  // ---- stage W1, W2
  for (int q = t; q < 64 * 64; q += 256) {
    uS.wm.w1[q >> 6][q & 63] = W1[q];
    uS.wm.w2[q >> 6][q & 63] = W2[q];
  }
  __syncthreads();

  // ---- f1 = sim@W1^T + b1 ; f2 = sim@W2^T + b2
  for (int u = t; u < S * NB; u += 256) {
    const int s = u >> 6, n = u & 63;
    float a1 = sB1[n], a2 = sB2[n];
    for (int n2 = 0; n2 < NB; ++n2) {
      const float sv = simm[s][n2];
      a1 += sv * uS.wm.w1[n][n2];
      a2 += sv * uS.wm.w2[n][n2];
    }
    u2.ff.f1[s][n] = a1;
    u2.ff.f2[s][n] = a2;
  }
  __syncthreads();

  // ---- G[s][t2] = f1[s]·f2[t2]
  for (int u = t; u < S * S; u += 256) {
    const int s = u / S, t2 = u % S;
    float gacc = 0.f;
    for (int n = 0; n < NB; ++n) gacc += u2.ff.f1[s][n] * u2.ff.f2[t2][n];
    u3.G[s][t2] = gacc;
  }
  __syncthreads();
  // row softmax of G (in place); simcv[t2] = sim[t2]·cv in parallel
  if (t < S) {
    float m = -1e30f;
    for (int t2 = 0; t2 < S; ++t2) m = fmaxf(m, u3.G[t][t2]);
    float sum = 0.f;
    for (int t2 = 0; t2 < S; ++t2) {
      const float e = expf(u3.G[t][t2] - m);
      u3.G[t][t2] = e;
      sum += e;
    }
    const float r = 1.f / sum;
    for (int t2 = 0; t2 < S; ++t2) u3.G[t][t2] *= r;
  } else if (t >= 64 && t < 64 + S) {
    const int t2 = t - 64;
    float a = 0.f;
    for (int n = 0; n < NB; ++n) a += simm[t2][n] * sCv[n];
    sSimcv[t2] = a;
  }
  __syncthreads();
  // out_s = tanh(gw[s]·simcv + bconst)
  if (t < S) {
    float a = 0.f;
    for (int t2 = 0; t2 < S; ++t2) a += u3.G[t][t2] * sSimcv[t2];
    sRed[t] = tanhf(a + sBconst);
  }
  __syncthreads();
  if (t == 0) {
    float a = 0.f;
    for (int s = 0; s < S; ++s) a += sRed[s];
    out[ii * NC + ci] = a * (1.f / 36.f);
  }
}

extern "C" void kernel_launch(void* const* d_in, const int* in_sizes, int n_in,
                              void* d_out, int out_size, void* d_ws, size_t ws_size,
                              hipStream_t stream) {
  const float* images   = (const float*)d_in[0];
  const float* captions = (const float*)d_in[1];
  // d_in[2] = cap_lens (unused: reference uniformizes to full length)
  const float* delt  = (const float*)d_in[3];
  const float* W1    = (const float*)d_in[4];
  const float* b1    = (const float*)d_in[5];
  const float* W2    = (const float*)d_in[6];
  const float* b2    = (const float*)d_in[7];
  const float* convW = (const float*)d_in[8];
  const float* convB = (const float*)d_in[9];
  const float* Wm    = (const float*)d_in[10];
  const float* bm    = (const float*)d_in[11];
  const float* V     = (const float*)d_in[12];
  const float* g     = (const float*)d_in[13];
  const float* bo    = (const float*)d_in[14];
  float* ws  = (float*)d_ws;
  float* out = (float*)d_out;

  prep_kernel<<<1, 256, 0, stream>>>(convW, convB, Wm, bm, V, g, bo, ws);
  i2t_kernel<<<dim3(NI * NC), 256, 0, stream>>>(images, captions, delt, W1, b1, W2, b2, ws, out);
}

// Round 2
// 376.048 us; speedup vs baseline: 1.6724x; 1.6724x over previous
//
#include <hip/hip_runtime.h>

#define EPSF 1e-8f

constexpr int NI = 48, NC = 48, S = 36, W = 32, D = 1024, NB = 64;
constexpr int CH = 64;            // k-chunk
constexpr int NCH = D / CH;       // 16
constexpr int ST1 = CH + 8;       // 72: pass-1 staging stride (f16)
constexpr int STT = 56;           // capT stride (f16)
constexpr int STI = 68;           // img32 stride (f32)
constexpr int STC = 52;           // ctxT stride (f32)
constexpr int STH = 72;           // sim_hl / M / yhl stride (f16)
constexpr int STA = 40;           // attn_hl stride (f16)

typedef _Float16 half8 __attribute__((ext_vector_type(8)));
typedef _Float16 half4 __attribute__((ext_vector_type(4)));
typedef float f32x4 __attribute__((ext_vector_type(4)));

__device__ __forceinline__ f32x4 mfma16(half8 a, half8 b, f32x4 c) {
  return __builtin_amdgcn_mfma_f32_16x16x32_f16(a, b, c, 0, 0, 0);
}

// ---------------- prep: fold conv/MeanOut/out-linear into cv[64], bconst;
// M = W1^T W2 (f16 hi/lo), u = W2^T b1 ----------------
__global__ __launch_bounds__(256) void prep_kernel(
    const float* __restrict__ W1, const float* __restrict__ b1,
    const float* __restrict__ W2,
    const float* __restrict__ convW, const float* __restrict__ convB,
    const float* __restrict__ Wm, const float* __restrict__ bm,
    const float* __restrict__ V, const float* __restrict__ g,
    const float* __restrict__ bo, float* __restrict__ ws) {
  __shared__ float sW1[64][68];
  __shared__ float sW2[64][68];
  __shared__ float wn[256];
  __shared__ float wv[64];
  __shared__ float vscale;
  const int t = threadIdx.x;
  for (int q = t; q < 2048; q += 256) {
    const int m = q >> 10, r = (q >> 4) & 63, c4 = (q & 15) * 4;
    const float* src = (m == 0 ? W1 : W2) + r * 64 + c4;
    float4 v = *reinterpret_cast<const float4*>(src);
    float* dst = (m == 0) ? &sW1[r][c4] : &sW2[r][c4];
    dst[0] = v.x; dst[1] = v.y; dst[2] = v.z; dst[3] = v.w;
  }
  if (t == 0) {
    float s = 0.f;
    for (int h = 0; h < 256; ++h) s += V[h] * V[h];
    vscale = g[0] / sqrtf(s);
  }
  __syncthreads();
  wn[t] = V[t] * vscale;
  __syncthreads();
  if (t < 64) {
    float acc = 0.f;
    for (int h = 0; h < 256; ++h)
      acc += 0.5f * (Wm[t * 512 + 2 * h] + Wm[t * 512 + 2 * h + 1]) * wn[h];
    wv[t] = acc;
  }
  __syncthreads();
  if (t < 64) {
    float acc = 0.f;
    for (int m = 0; m < 64; ++m) {
      float ce = 0.f;
      for (int k = 0; k < 8; ++k) ce += convW[k * 4096 + t * 64 + m];
      acc += 0.125f * ce * wv[m];
    }
    ws[t] = acc;  // cv
  }
  if (t == 0) {
    float bh = 0.f;
    for (int h = 0; h < 256; ++h) bh += 0.5f * (bm[2 * h] + bm[2 * h + 1]) * wn[h];
    float bc = 0.f;
    for (int m = 0; m < 64; ++m) bc += convB[m] * wv[m];
    ws[64] = bh + bc + bo[0];  // bconst
  }
  if (t < 64) {  // u = W2^T b1
    float a = 0.f;
    for (int k = 0; k < 64; ++k) a += b1[k] * sW2[k][t];
    ws[66 + t] = a;
  }
  // M = W1^T W2 -> f16 hi/lo at ws+132
  {
    const int i = t >> 2, j0 = (t & 3) * 16;
    float acc[16];
#pragma unroll
    for (int jj = 0; jj < 16; ++jj) acc[jj] = 0.f;
    for (int k = 0; k < 64; ++k) {
      const float w1v = sW1[k][i];
#pragma unroll
      for (int jj = 0; jj < 16; ++jj) acc[jj] += w1v * sW2[k][j0 + jj];
    }
    _Float16* wsM = reinterpret_cast<_Float16*>(ws + 132);
#pragma unroll
    for (int jj = 0; jj < 16; ++jj) {
      const float x = acc[jj];
      const _Float16 h = (_Float16)x;
      wsM[i * 64 + j0 + jj] = h;
      wsM[4096 + i * 64 + j0 + jj] = (_Float16)(x - (float)h);
    }
  }
}

// ---------------- main: one block per (caption, image) pair ----------------
__global__ __launch_bounds__(256, 2) void i2t_kernel(
    const float* __restrict__ images, const float* __restrict__ captions,
    const float* __restrict__ delt, const float* __restrict__ ws,
    float* __restrict__ out) {
  __shared__ union {
    struct { _Float16 cap[2][32][ST1]; _Float16 img[2][48][ST1]; } s1;  // 23040 B
    float lpart[4][32][36];                                             // 18432 B
    struct { _Float16 capT[2][64][STT]; float img32[36][STI]; } s2;     // 24128 B
    _Float16 M[2][64][STH];                                             // 18432 B
    float G[36][52];                                                    // 7488 B
  } rA;
  __shared__ union {
    float La[32][37];           // 4736 B
    float ctxT[64][STC];        // 13312 B
    _Float16 yhl[2][48][STH];   // 13824 B
  } rB;
  __shared__ _Float16 attn_hl[2][48][STA];  // 7680 B
  __shared__ _Float16 sim_hl[2][48][STH];   // 13824 B
  __shared__ float wrcp[32];
  __shared__ float sDelt[64], sCv[64], sU[64];
  __shared__ float sP[36], sScv[36], sRed[36];
  __shared__ float sBconst;

  const int t = threadIdx.x;
  const int lane = t & 63, wid = t >> 6;
  const int mrow = lane & 15, grp = lane >> 4;
  const int bid = blockIdx.x;
  const int xcd = bid & 7, l = bid >> 3;
  const int ci = (xcd >> 1) * 12 + (l % 12);
  const int ii = (xcd & 1) * 24 + (l / 12);
  const float* cap = captions + ci * (W * D);
  const float* img = images + ii * (S * D);
  const f32x4 zero4 = {0.f, 0.f, 0.f, 0.f};

  if (t < 64) { sDelt[t] = delt[t]; sCv[t] = ws[t]; sU[t] = ws[66 + t]; }
  if (t == 64) sBconst = ws[64];

  // ================= pass 1: L[w][s] via MFMA (split-K over waves) ==========
  f32x4 acc1[2][3];
#pragma unroll
  for (int mt = 0; mt < 2; ++mt)
#pragma unroll
    for (int nt = 0; nt < 3; ++nt) acc1[mt][nt] = zero4;

  for (int ch = 0; ch < NCH; ++ch) {
    const int d0 = ch * CH;
    __syncthreads();
    for (int q = t; q < 1088; q += 256) {   // (32+36) rows x 16 float4
      const int row = q >> 4, c4 = (q & 15) * 4;
      const float* src = (row < 32) ? (cap + row * D + d0 + c4)
                                    : (img + (row - 32) * D + d0 + c4);
      float4 v = *reinterpret_cast<const float4*>(src);
      half4 hh, ll;
      hh[0] = (_Float16)v.x; ll[0] = (_Float16)(v.x - (float)hh[0]);
      hh[1] = (_Float16)v.y; ll[1] = (_Float16)(v.y - (float)hh[1]);
      hh[2] = (_Float16)v.z; ll[2] = (_Float16)(v.z - (float)hh[2]);
      hh[3] = (_Float16)v.w; ll[3] = (_Float16)(v.w - (float)hh[3]);
      _Float16* dh = (row < 32) ? &rA.s1.cap[0][row][c4] : &rA.s1.img[0][row - 32][c4];
      _Float16* dl = (row < 32) ? &rA.s1.cap[1][row][c4] : &rA.s1.img[1][row - 32][c4];
      *reinterpret_cast<half4*>(dh) = hh;
      *reinterpret_cast<half4*>(dl) = ll;
    }
    __syncthreads();
    if ((ch & 3) == wid) {
#pragma unroll
      for (int ks = 0; ks < 2; ++ks) {
        const int ko = ks * 32 + grp * 8;
        half8 ah[2], al[2], bh[3], bl[3];
#pragma unroll
        for (int mt = 0; mt < 2; ++mt) {
          ah[mt] = *reinterpret_cast<const half8*>(&rA.s1.cap[0][mt * 16 + mrow][ko]);
          al[mt] = *reinterpret_cast<const half8*>(&rA.s1.cap[1][mt * 16 + mrow][ko]);
        }
#pragma unroll
        for (int nt = 0; nt < 3; ++nt) {
          bh[nt] = *reinterpret_cast<const half8*>(&rA.s1.img[0][nt * 16 + mrow][ko]);
          bl[nt] = *reinterpret_cast<const half8*>(&rA.s1.img[1][nt * 16 + mrow][ko]);
        }
#pragma unroll
        for (int mt = 0; mt < 2; ++mt)
#pragma unroll
          for (int nt = 0; nt < 3; ++nt) {
            acc1[mt][nt] = mfma16(ah[mt], bh[nt], acc1[mt][nt]);
            acc1[mt][nt] = mfma16(ah[mt], bl[nt], acc1[mt][nt]);
            acc1[mt][nt] = mfma16(al[mt], bh[nt], acc1[mt][nt]);
          }
      }
    }
  }
  __syncthreads();
#pragma unroll
  for (int mt = 0; mt < 2; ++mt)
#pragma unroll
    for (int nt = 0; nt < 3; ++nt)
#pragma unroll
      for (int r = 0; r < 4; ++r) {
        const int w = mt * 16 + grp * 4 + r;
        const int s = nt * 16 + mrow;
        if (s < S) rA.lpart[wid][w][s] = acc1[mt][nt][r];
      }
  __syncthreads();
  {  // reduce split-K + leaky_relu
    const float* lp = &rA.lpart[0][0][0];
    for (int e = t; e < W * S; e += 256) {
      float x = lp[e] + lp[e + 1152] + lp[e + 2304] + lp[e + 3456];
      x = x > 0.f ? x : 0.1f * x;
      rB.La[e / S][e % S] = x;
    }
  }
  __syncthreads();
  if (t < W) {  // 1/l2norm over regions per word
    float sum = 0.f;
    for (int s = 0; s < S; ++s) { float v = rB.La[t][s]; sum += v * v; }
    wrcp[t] = 1.f / (sqrtf(sum) + EPSF);
  }
  __syncthreads();
  if (t < S) {  // softmax over words per region -> attn f16 hi/lo
    float lw[32];
    float m = -1e30f;
#pragma unroll
    for (int w = 0; w < W; ++w) {
      float v = 9.f * rB.La[w][t] * wrcp[w];
      lw[w] = v;
      m = fmaxf(m, v);
    }
    float sum = 0.f;
#pragma unroll
    for (int w = 0; w < W; ++w) { lw[w] = expf(lw[w] - m); sum += lw[w]; }
    const float r = 1.f / sum;
#pragma unroll
    for (int w = 0; w < W; ++w) {
      float a = lw[w] * r;
      _Float16 h = (_Float16)a;
      attn_hl[0][t][w] = h;
      attn_hl[1][t][w] = (_Float16)(a - (float)h);
    }
  }
  __syncthreads();

  // ================= pass 2: ctx via MFMA -> blockwise cosine sim ==========
  half8 a2h[3], a2l[3];
#pragma unroll
  for (int mt = 0; mt < 3; ++mt) {
    a2h[mt] = *reinterpret_cast<const half8*>(&attn_hl[0][mt * 16 + mrow][grp * 8]);
    a2l[mt] = *reinterpret_cast<const half8*>(&attn_hl[1][mt * 16 + mrow][grp * 8]);
  }
  for (int ch = 0; ch < NCH; ++ch) {
    const int d0 = ch * CH;
    __syncthreads();
    {  // stage cap transposed (f16 hi/lo): one 8w-chunk per thread
      const int dl = t & 63, wb = (t >> 6) * 8;
      half8 hh, ll;
#pragma unroll
      for (int k = 0; k < 8; ++k) {
        float x = cap[(wb + k) * D + d0 + dl];
        hh[k] = (_Float16)x;
        ll[k] = (_Float16)(x - (float)hh[k]);
      }
      *reinterpret_cast<half8*>(&rA.s2.capT[0][dl][wb]) = hh;
      *reinterpret_cast<half8*>(&rA.s2.capT[1][dl][wb]) = ll;
    }
    for (int q = t; q < 576; q += 256) {  // stage img f32
      const int sr = q >> 4, c4 = (q & 15) * 4;
      float4 v = *reinterpret_cast<const float4*>(img + sr * D + d0 + c4);
      *reinterpret_cast<float4*>(&rA.s2.img32[sr][c4]) = v;
    }
    __syncthreads();
    {  // ctx MFMA: wave wid owns d-block wid
      const int dloc = wid * 16 + mrow;
      half8 b_h = *reinterpret_cast<const half8*>(&rA.s2.capT[0][dloc][grp * 8]);
      half8 b_l = *reinterpret_cast<const half8*>(&rA.s2.capT[1][dloc][grp * 8]);
#pragma unroll
      for (int mt = 0; mt < 3; ++mt) {
        f32x4 acc = zero4;
        acc = mfma16(a2h[mt], b_h, acc);
        acc = mfma16(a2h[mt], b_l, acc);
        acc = mfma16(a2l[mt], b_h, acc);
        const int s0 = mt * 16 + grp * 4;
        if (s0 < S) *reinterpret_cast<f32x4*>(&rB.ctxT[dloc][s0]) = acc;
      }
    }
    __syncthreads();
    if (t < 144) {  // blockwise cosine units: (s, nb_local)
      const int s = t % 36, nbl = t / 36;
      const int n = ch * 4 + nbl;
      float dt = 0.f, dc = 0.f, dq = 0.f;
#pragma unroll
      for (int j4 = 0; j4 < 4; ++j4) {
        f32x4 qv = *reinterpret_cast<const f32x4*>(&rA.s2.img32[s][nbl * 16 + j4 * 4]);
#pragma unroll
        for (int jj = 0; jj < 4; ++jj) {
          float cx = rB.ctxT[nbl * 16 + j4 * 4 + jj][s];
          float q = qv[jj];
          dt += q * cx; dc += cx * cx; dq += q * q;
        }
      }
      float sim = dt / fmaxf(sqrtf(dq) * sqrtf(dc), EPSF) * sDelt[n];
      _Float16 h = (_Float16)sim;
      sim_hl[0][s][n] = h;
      sim_hl[1][s][n] = (_Float16)(sim - (float)h);
    }
  }
  __syncthreads();

  // ================= y = sim·M^T ; G = sim·y^T ; softmax+out ==============
  for (int q = t; q < 1024; q += 256) {  // stage M f16 hi/lo
    const int hl = q >> 9, row = (q >> 3) & 63, c8 = (q & 7) * 8;
    const _Float16* wsM = reinterpret_cast<const _Float16*>(ws + 132);
    *reinterpret_cast<half8*>(&rA.M[hl][row][c8]) =
        *reinterpret_cast<const half8*>(wsM + hl * 4096 + row * 64 + c8);
  }
  __syncthreads();
  for (int tid = wid; tid < 12; tid += 4) {  // y-GEMM: 3x4 tiles
    const int mt = tid >> 2, nt = tid & 3;
    f32x4 acc = zero4;
#pragma unroll
    for (int ks = 0; ks < 2; ++ks) {
      const int ko = ks * 32 + grp * 8;
      half8 a_h = *reinterpret_cast<const half8*>(&sim_hl[0][mt * 16 + mrow][ko]);
      half8 a_l = *reinterpret_cast<const half8*>(&sim_hl[1][mt * 16 + mrow][ko]);
      half8 b_h = *reinterpret_cast<const half8*>(&rA.M[0][nt * 16 + mrow][ko]);
      half8 b_l = *reinterpret_cast<const half8*>(&rA.M[1][nt * 16 + mrow][ko]);
      acc = mfma16(a_h, b_h, acc);
      acc = mfma16(a_h, b_l, acc);
      acc = mfma16(a_l, b_h, acc);
    }
#pragma unroll
    for (int r = 0; r < 4; ++r) {
      const int srow = mt * 16 + grp * 4 + r;
      const int icol = nt * 16 + mrow;
      float x = acc[r];
      _Float16 h = (_Float16)x;
      rB.yhl[0][srow][icol] = h;
      rB.yhl[1][srow][icol] = (_Float16)(x - (float)h);
    }
  }
  __syncthreads();
  for (int tid = wid; tid < 9; tid += 4) {  // G-GEMM: 3x3 tiles
    const int mt = tid / 3, nt = tid % 3;
    f32x4 acc = zero4;
#pragma unroll
    for (int ks = 0; ks < 2; ++ks) {
      const int ko = ks * 32 + grp * 8;
      half8 a_h = *reinterpret_cast<const half8*>(&sim_hl[0][mt * 16 + mrow][ko]);
      half8 a_l = *reinterpret_cast<const half8*>(&sim_hl[1][mt * 16 + mrow][ko]);
      half8 b_h = *reinterpret_cast<const half8*>(&rB.yhl[0][nt * 16 + mrow][ko]);
      half8 b_l = *reinterpret_cast<const half8*>(&rB.yhl[1][nt * 16 + mrow][ko]);
      acc = mfma16(a_h, b_h, acc);
      acc = mfma16(a_h, b_l, acc);
      acc = mfma16(a_l, b_h, acc);
    }
#pragma unroll
    for (int r = 0; r < 4; ++r) {
      const int srow = mt * 16 + grp * 4 + r;
      const int tcol = nt * 16 + mrow;
      if (srow < S) rA.G[srow][tcol] = acc[r];
    }
  }
  __syncthreads();
  if (t < S) {  // p[t] = u·sim_t
    float a = 0.f;
#pragma unroll
    for (int n = 0; n < 64; ++n)
      a += ((float)sim_hl[0][t][n] + (float)sim_hl[1][t][n]) * sU[n];
    sP[t] = a;
  } else if (t >= 64 && t < 64 + S) {  // simcv[t] = cv·sim_t
    const int r = t - 64;
    float a = 0.f;
#pragma unroll
    for (int n = 0; n < 64; ++n)
      a += ((float)sim_hl[0][r][n] + (float)sim_hl[1][r][n]) * sCv[n];
    sScv[r] = a;
  }
  __syncthreads();
  if (t < S) {  // fused row-softmax(G + p) · simcv -> tanh
    float lg[36];
    float m = -1e30f;
#pragma unroll
    for (int t2 = 0; t2 < S; ++t2) {
      lg[t2] = rA.G[t][t2] + sP[t2];
      m = fmaxf(m, lg[t2]);
    }
    float se = 0.f, sv = 0.f;
#pragma unroll
    for (int t2 = 0; t2 < S; ++t2) {
      float e = expf(lg[t2] - m);
      se += e; sv += e * sScv[t2];
    }
    sRed[t] = tanhf(sv / se + sBconst);
  }
  __syncthreads();
  if (t == 0) {
    float a = 0.f;
    for (int s = 0; s < S; ++s) a += sRed[s];
    out[ii * NC + ci] = a * (1.f / 36.f);
  }
}

extern "C" void kernel_launch(void* const* d_in, const int* in_sizes, int n_in,
                              void* d_out, int out_size, void* d_ws, size_t ws_size,
                              hipStream_t stream) {
  const float* images   = (const float*)d_in[0];
  const float* captions = (const float*)d_in[1];
  // d_in[2] = cap_lens (unused: reference uniformizes to full length)
  const float* delt  = (const float*)d_in[3];
  const float* W1    = (const float*)d_in[4];
  const float* b1    = (const float*)d_in[5];
  const float* W2    = (const float*)d_in[6];
  // d_in[7] = b2: cancels inside the row-softmax, unused
  const float* convW = (const float*)d_in[8];
  const float* convB = (const float*)d_in[9];
  const float* Wm    = (const float*)d_in[10];
  const float* bm    = (const float*)d_in[11];
  const float* V     = (const float*)d_in[12];
  const float* g     = (const float*)d_in[13];
  const float* bo    = (const float*)d_in[14];
  float* ws  = (float*)d_ws;
  float* out = (float*)d_out;

  prep_kernel<<<1, 256, 0, stream>>>(W1, b1, W2, convW, convB, Wm, bm, V, g, bo, ws);
  i2t_kernel<<<dim3(NI * NC), 256, 0, stream>>>(images, captions, delt, ws, out);
}

// Round 3
// 344.813 us; speedup vs baseline: 1.8239x; 1.0906x over previous
//
#include <hip/hip_runtime.h>

#define EPSF 1e-8f

constexpr int NI = 48, NC = 48, S = 36, W = 32, D = 1024, NB = 64;
constexpr int CH = 64;            // k-chunk
constexpr int NCH = D / CH;       // 16

typedef _Float16 half8 __attribute__((ext_vector_type(8)));
typedef _Float16 half4 __attribute__((ext_vector_type(4)));
typedef float f32x4 __attribute__((ext_vector_type(4)));

__device__ __forceinline__ f32x4 mfma16(half8 a, half8 b, f32x4 c) {
  return __builtin_amdgcn_mfma_f32_16x16x32_f16(a, b, c, 0, 0, 0);
}

// ---- ws layout ----
constexpr size_t OFF0   = 17408;                       // bytes; floats [0..4352) = prep data
constexpr size_t SZ_CAP = (size_t)48 * 32 * 1024 * 2;  // f16 bytes
constexpr size_t SZ_IMG = (size_t)48 * 36 * 1024 * 2;
constexpr size_t OFF_CAPH  = OFF0;
constexpr size_t OFF_CAPL  = OFF_CAPH + SZ_CAP;
constexpr size_t OFF_CAPTH = OFF_CAPL + SZ_CAP;
constexpr size_t OFF_CAPTL = OFF_CAPTH + SZ_CAP;
constexpr size_t OFF_IMGH  = OFF_CAPTL + SZ_CAP;
constexpr size_t OFF_IMGL  = OFF_IMGH + SZ_IMG;
constexpr size_t OFF_DQ    = OFF_IMGL + SZ_IMG;
constexpr size_t WS_NEED   = OFF_DQ + (size_t)48 * 36 * 64 * 4;

// ---------------- prep: fold conv/MeanOut/out-linear into cv[64], bconst;
// M = W1^T W2 (f16 hi/lo), u = W2^T b1 ----------------
__global__ __launch_bounds__(256) void prep_kernel(
    const float* __restrict__ W1, const float* __restrict__ b1,
    const float* __restrict__ W2,
    const float* __restrict__ convW, const float* __restrict__ convB,
    const float* __restrict__ Wm, const float* __restrict__ bm,
    const float* __restrict__ V, const float* __restrict__ g,
    const float* __restrict__ bo, float* __restrict__ ws) {
  __shared__ float sW1[64][68];
  __shared__ float sW2[64][68];
  __shared__ float wn[256];
  __shared__ float wv[64];
  __shared__ float vscale;
  const int t = threadIdx.x;
  for (int q = t; q < 2048; q += 256) {
    const int m = q >> 10, r = (q >> 4) & 63, c4 = (q & 15) * 4;
    const float* src = (m == 0 ? W1 : W2) + r * 64 + c4;
    float4 v = *reinterpret_cast<const float4*>(src);
    float* dst = (m == 0) ? &sW1[r][c4] : &sW2[r][c4];
    dst[0] = v.x; dst[1] = v.y; dst[2] = v.z; dst[3] = v.w;
  }
  if (t == 0) {
    float s = 0.f;
    for (int h = 0; h < 256; ++h) s += V[h] * V[h];
    vscale = g[0] / sqrtf(s);
  }
  __syncthreads();
  wn[t] = V[t] * vscale;
  __syncthreads();
  if (t < 64) {
    float acc = 0.f;
    for (int h = 0; h < 256; ++h)
      acc += 0.5f * (Wm[t * 512 + 2 * h] + Wm[t * 512 + 2 * h + 1]) * wn[h];
    wv[t] = acc;
  }
  __syncthreads();
  if (t < 64) {
    float acc = 0.f;
    for (int m = 0; m < 64; ++m) {
      float ce = 0.f;
      for (int k = 0; k < 8; ++k) ce += convW[k * 4096 + t * 64 + m];
      acc += 0.125f * ce * wv[m];
    }
    ws[t] = acc;  // cv
  }
  if (t == 0) {
    float bh = 0.f;
    for (int h = 0; h < 256; ++h) bh += 0.5f * (bm[2 * h] + bm[2 * h + 1]) * wn[h];
    float bc = 0.f;
    for (int m = 0; m < 64; ++m) bc += convB[m] * wv[m];
    ws[64] = bh + bc + bo[0];  // bconst
  }
  if (t < 64) {  // u = W2^T b1
    float a = 0.f;
    for (int k = 0; k < 64; ++k) a += b1[k] * sW2[k][t];
    ws[66 + t] = a;
  }
  // M = W1^T W2 -> f16 hi/lo at ws+132
  {
    const int i = t >> 2, j0 = (t & 3) * 16;
    float acc[16];
#pragma unroll
    for (int jj = 0; jj < 16; ++jj) acc[jj] = 0.f;
    for (int k = 0; k < 64; ++k) {
      const float w1v = sW1[k][i];
#pragma unroll
      for (int jj = 0; jj < 16; ++jj) acc[jj] += w1v * sW2[k][j0 + jj];
    }
    _Float16* wsM = reinterpret_cast<_Float16*>(ws + 132);
#pragma unroll
    for (int jj = 0; jj < 16; ++jj) {
      const float x = acc[jj];
      const _Float16 h = (_Float16)x;
      wsM[i * 64 + j0 + jj] = h;
      wsM[4096 + i * 64 + j0 + jj] = (_Float16)(x - (float)h);
    }
  }
}

// ---------------- convert captions: row-major + transposed f16 hi/lo ----------------
__global__ __launch_bounds__(256) void conv_cap(
    const float* __restrict__ cap, _Float16* __restrict__ capH,
    _Float16* __restrict__ capL, _Float16* __restrict__ capTH,
    _Float16* __restrict__ capTL) {
  __shared__ _Float16 tH[64][40], tL[64][40];
  const int t = threadIdx.x;
  const int c = blockIdx.x, ch = blockIdx.y;
  const int d0 = ch * 64;
  for (int q = t; q < 512; q += 256) {
    const int w = q >> 4, c4 = (q & 15) * 4;
    const size_t gi = ((size_t)c * 32 + w) * 1024 + d0 + c4;
    float4 v = *reinterpret_cast<const float4*>(cap + gi);
    half4 hh, ll;
    hh[0] = (_Float16)v.x; ll[0] = (_Float16)(v.x - (float)hh[0]);
    hh[1] = (_Float16)v.y; ll[1] = (_Float16)(v.y - (float)hh[1]);
    hh[2] = (_Float16)v.z; ll[2] = (_Float16)(v.z - (float)hh[2]);
    hh[3] = (_Float16)v.w; ll[3] = (_Float16)(v.w - (float)hh[3]);
    *reinterpret_cast<half4*>(capH + gi) = hh;
    *reinterpret_cast<half4*>(capL + gi) = ll;
#pragma unroll
    for (int j = 0; j < 4; ++j) { tH[c4 + j][w] = hh[j]; tL[c4 + j][w] = ll[j]; }
  }
  __syncthreads();
  for (int q = t; q < 512; q += 256) {
    const int hl = q >> 8, dd = (q >> 2) & 63, w8 = (q & 3) * 8;
    half8 v = *reinterpret_cast<const half8*>(hl ? &tL[dd][w8] : &tH[dd][w8]);
    _Float16* dst = (hl ? capTL : capTH) + ((size_t)c * 1024 + d0 + dd) * 32 + w8;
    *reinterpret_cast<half8*>(dst) = v;
  }
}

// ---------------- convert images (row-major hi/lo) + per-image dq table ----------------
__global__ __launch_bounds__(256) void conv_img(
    const float* __restrict__ img, _Float16* __restrict__ imgH,
    _Float16* __restrict__ imgL, float* __restrict__ dq) {
  const int t = threadIdx.x;
  const int i = blockIdx.x, ch = blockIdx.y;
  const int d0 = ch * 64;
  for (int q = t; q < 576; q += 256) {
    const int s = q >> 4, c4 = (q & 15) * 4;
    const size_t gi = ((size_t)i * 36 + s) * 1024 + d0 + c4;
    float4 v = *reinterpret_cast<const float4*>(img + gi);
    half4 hh, ll;
    hh[0] = (_Float16)v.x; ll[0] = (_Float16)(v.x - (float)hh[0]);
    hh[1] = (_Float16)v.y; ll[1] = (_Float16)(v.y - (float)hh[1]);
    hh[2] = (_Float16)v.z; ll[2] = (_Float16)(v.z - (float)hh[2]);
    hh[3] = (_Float16)v.w; ll[3] = (_Float16)(v.w - (float)hh[3]);
    *reinterpret_cast<half4*>(imgH + gi) = hh;
    *reinterpret_cast<half4*>(imgL + gi) = ll;
  }
  if (t < 144) {  // dq[i][s][nb] = sum over 16 d of img^2
    const int s = t % 36, nbl = t / 36;
    const float* p = img + ((size_t)i * 36 + s) * 1024 + d0 + nbl * 16;
    float a = 0.f;
#pragma unroll
    for (int j = 0; j < 16; ++j) a += p[j] * p[j];
    dq[((size_t)i * 36 + s) * 64 + ch * 4 + nbl] = a;
  }
}

// ---------------- fast main: one block per (caption, image) pair ----------------
__global__ __launch_bounds__(256, 2) void i2t_fast(
    const float* __restrict__ images,
    const _Float16* __restrict__ capH, const _Float16* __restrict__ capL,
    const _Float16* __restrict__ capTH, const _Float16* __restrict__ capTL,
    const _Float16* __restrict__ imgH, const _Float16* __restrict__ imgL,
    const float* __restrict__ dqTab, const float* __restrict__ delt,
    const float* __restrict__ ws, float* __restrict__ out) {
  __shared__ union {
    struct { _Float16 cap[2][2][32][72]; _Float16 img[2][2][36][72]; } p1;  // 39168 B
    struct { _Float16 capT[2][2][64][32]; float img32[2][36][68]; } p2;     // 35968 B
    struct { float lpart[2][32][37]; float G[36][52]; } t1;                 // 16960 B
    _Float16 M[2][64][72];                                                  // 18432 B
  } uA;
  __shared__ union {
    float La[32][37];          // 4736 B
    _Float16 yhl[2][36][72];   // 10368 B
  } uB;
  __shared__ _Float16 attn_hl[2][36][40];  // 5760 B
  __shared__ _Float16 sim_hl[2][36][72];   // 10368 B
  __shared__ float sDq[36][68];            // 9792 B
  __shared__ float wrcp[32];
  __shared__ float sDelt[64], sCv[64], sU[64];
  __shared__ float sP[36], sScv[36], sRed[36];
  __shared__ float sBconst;

  const int t = threadIdx.x;
  const int lane = t & 63, wid = t >> 6;
  const int c = lane & 15, g = lane >> 4;
  const int bid = blockIdx.x;
  const int xcd = bid & 7, l = bid >> 3;
  const int ci = (xcd >> 1) * 12 + (l % 12);
  const int ii = (xcd & 1) * 24 + (l / 12);
  const f32x4 zero4 = {0.f, 0.f, 0.f, 0.f};

  auto p1_load = [&](int ch, half8 r[5]) {
    const int d0 = ch * CH;
#pragma unroll
    for (int k = 0; k < 5; ++k) {
      const int u = t + k * 256;
      if (u < 1088) {
        const _Float16* src;
        if (u < 512) {
          const int hl = u >> 8, w = (u >> 3) & 31, k8 = (u & 7) * 8;
          src = (hl ? capL : capH) + ((size_t)ci * 32 + w) * 1024 + d0 + k8;
        } else {
          const int v = u - 512;
          const int hl = v / 288, rem = v % 288;
          const int s = rem >> 3, k8 = (rem & 7) * 8;
          src = (hl ? imgL : imgH) + ((size_t)ii * 36 + s) * 1024 + d0 + k8;
        }
        r[k] = *reinterpret_cast<const half8*>(src);
      }
    }
  };
  auto p1_store = [&](int buf, half8 r[5]) {
#pragma unroll
    for (int k = 0; k < 5; ++k) {
      const int u = t + k * 256;
      if (u < 1088) {
        _Float16* dst;
        if (u < 512) {
          const int hl = u >> 8, w = (u >> 3) & 31, k8 = (u & 7) * 8;
          dst = &uA.p1.cap[buf][hl][w][k8];
        } else {
          const int v = u - 512;
          const int hl = v / 288, rem = v % 288;
          const int s = rem >> 3, k8 = (rem & 7) * 8;
          dst = &uA.p1.img[buf][hl][s][k8];
        }
        *reinterpret_cast<half8*>(dst) = r[k];
      }
    }
  };

  // start first chunk's loads early
  half8 r1[5];
  p1_load(0, r1);

  if (t < 64) { sDelt[t] = delt[t]; sCv[t] = ws[t]; sU[t] = ws[66 + t]; }
  if (t == 64) sBconst = ws[64];
  for (int q = t; q < 576; q += 256) {  // per-image dq table -> LDS
    const int s = q >> 4, c4 = (q & 15) * 4;
    f32x4 v = *reinterpret_cast<const f32x4*>(dqTab + ((size_t)ii * 36 + s) * 64 + c4);
    *reinterpret_cast<f32x4*>(&sDq[s][c4]) = v;
  }

  // ================= pass 1: L[w][s] via MFMA =================
  // wave = (k-slice, w-tile); per chunk each wave: 1x3 tiles x 3 hi/lo terms
  const int slice = wid & 1, wt = wid >> 1;
  f32x4 acc1[3];
#pragma unroll
  for (int nt = 0; nt < 3; ++nt) acc1[nt] = zero4;

  int pbuf = 0;
  for (int ch = 0; ch < NCH; ++ch) {
    p1_store(pbuf, r1);
    if (ch < NCH - 1) p1_load(ch + 1, r1);
    __syncthreads();
    const int ko = slice * 32 + g * 8;
    half8 ah = *reinterpret_cast<const half8*>(&uA.p1.cap[pbuf][0][wt * 16 + c][ko]);
    half8 al = *reinterpret_cast<const half8*>(&uA.p1.cap[pbuf][1][wt * 16 + c][ko]);
#pragma unroll
    for (int nt = 0; nt < 3; ++nt) {
      int br = nt * 16 + c; if (br > 35) br = 35;
      half8 bh = *reinterpret_cast<const half8*>(&uA.p1.img[pbuf][0][br][ko]);
      half8 bl = *reinterpret_cast<const half8*>(&uA.p1.img[pbuf][1][br][ko]);
      acc1[nt] = mfma16(ah, bh, acc1[nt]);
      acc1[nt] = mfma16(ah, bl, acc1[nt]);
      acc1[nt] = mfma16(al, bh, acc1[nt]);
    }
    pbuf ^= 1;
  }
  // write split-K partials (disjoint bytes from last compute buffer)
#pragma unroll
  for (int nt = 0; nt < 3; ++nt)
#pragma unroll
    for (int r = 0; r < 4; ++r) {
      const int s = nt * 16 + c;
      const int w = wt * 16 + 4 * g + r;
      if (s < S) uA.t1.lpart[slice][w][s] = acc1[nt][r];
    }
  __syncthreads();
  for (int e = t; e < W * S; e += 256) {  // reduce + leaky relu
    const int w = e / S, s = e % S;
    float x = uA.t1.lpart[0][w][s] + uA.t1.lpart[1][w][s];
    x = x > 0.f ? x : 0.1f * x;
    uB.La[w][s] = x;
  }
  __syncthreads();
  if (t < W) {  // 1/l2norm over regions per word
    float sum = 0.f;
    for (int s = 0; s < S; ++s) { float v = uB.La[t][s]; sum += v * v; }
    wrcp[t] = 1.f / (sqrtf(sum) + EPSF);
  }
  __syncthreads();
  if (t < S) {  // softmax over words per region -> attn f16 hi/lo
    float lw[32];
    float m = -1e30f;
#pragma unroll
    for (int w = 0; w < W; ++w) {
      float v = 9.f * uB.La[w][t] * wrcp[w];
      lw[w] = v;
      m = fmaxf(m, v);
    }
    float sum = 0.f;
#pragma unroll
    for (int w = 0; w < W; ++w) { lw[w] = expf(lw[w] - m); sum += lw[w]; }
    const float r = 1.f / sum;
#pragma unroll
    for (int w = 0; w < W; ++w) {
      float a = lw[w] * r;
      _Float16 h = (_Float16)a;
      attn_hl[0][t][w] = h;
      attn_hl[1][t][w] = (_Float16)(a - (float)h);
    }
  }
  __syncthreads();

  // ================= pass 2: ctx rows=d via MFMA, in-register cosine ========
  half8 b2h[3], b2l[3];
#pragma unroll
  for (int mt = 0; mt < 3; ++mt) {
    int br = mt * 16 + c; if (br > 35) br = 35;
    b2h[mt] = *reinterpret_cast<const half8*>(&attn_hl[0][br][g * 8]);
    b2l[mt] = *reinterpret_cast<const half8*>(&attn_hl[1][br][g * 8]);
  }
  auto p2_load = [&](int ch, half8 rc[2], f32x4 ri[3]) {
    const int d0 = ch * CH;
#pragma unroll
    for (int k = 0; k < 2; ++k) {
      const int u = t + k * 256;
      const int hl = u >> 8, dd = (u >> 2) & 63, w8 = (u & 3) * 8;
      const _Float16* src = (hl ? capTL : capTH) + ((size_t)ci * 1024 + d0 + dd) * 32 + w8;
      rc[k] = *reinterpret_cast<const half8*>(src);
    }
#pragma unroll
    for (int k = 0; k < 3; ++k) {
      const int u = t + k * 256;
      if (u < 576) {
        const int s = u >> 4, c4 = (u & 15) * 4;
        ri[k] = *reinterpret_cast<const f32x4*>(images + ((size_t)ii * 36 + s) * 1024 + d0 + c4);
      }
    }
  };
  auto p2_store = [&](int buf, half8 rc[2], f32x4 ri[3]) {
#pragma unroll
    for (int k = 0; k < 2; ++k) {
      const int u = t + k * 256;
      const int hl = u >> 8, dd = (u >> 2) & 63, w8 = (u & 3) * 8;
      char* base = (char*)&uA.p2.capT[buf][hl][0][0];
      *reinterpret_cast<half8*>(base + dd * 64 + ((w8 * 2) ^ ((dd & 3) << 4))) = rc[k];
    }
#pragma unroll
    for (int k = 0; k < 3; ++k) {
      const int u = t + k * 256;
      if (u < 576) {
        const int s = u >> 4, c4 = (u & 15) * 4;
        *reinterpret_cast<f32x4*>(&uA.p2.img32[buf][s][c4]) = ri[k];
      }
    }
  };

  half8 r2c[2];
  f32x4 r2i[3];
  p2_load(0, r2c, r2i);
  pbuf = 0;
  for (int ch = 0; ch < NCH; ++ch) {
    p2_store(pbuf, r2c, r2i);
    if (ch < NCH - 1) p2_load(ch + 1, r2c, r2i);
    __syncthreads();
    const int drow = wid * 16 + c;           // local d row (A operand)
    const int sw = (g * 16) ^ ((drow & 3) << 4);
    const char* c0b = (const char*)&uA.p2.capT[pbuf][0][0][0];
    const char* c1b = (const char*)&uA.p2.capT[pbuf][1][0][0];
    half8 Ah = *reinterpret_cast<const half8*>(c0b + drow * 64 + sw);
    half8 Al = *reinterpret_cast<const half8*>(c1b + drow * 64 + sw);
    const int nb = ch * 4 + wid;
#pragma unroll
    for (int mt = 0; mt < 3; ++mt) {
      f32x4 acc = zero4;
      acc = mfma16(Ah, b2h[mt], acc);
      acc = mfma16(Ah, b2l[mt], acc);
      acc = mfma16(Al, b2h[mt], acc);
      // lane holds ctx[d = wid*16 + 4g + r][s = mt*16 + c]
      const int s = mt * 16 + c;
      const int sc = s < S ? s : 35;
      f32x4 q = *reinterpret_cast<const f32x4*>(&uA.p2.img32[pbuf][sc][wid * 16 + 4 * g]);
      float dt = acc[0] * q[0] + acc[1] * q[1] + acc[2] * q[2] + acc[3] * q[3];
      float dc = acc[0] * acc[0] + acc[1] * acc[1] + acc[2] * acc[2] + acc[3] * acc[3];
      dt += __shfl_xor(dt, 16); dc += __shfl_xor(dc, 16);
      dt += __shfl_xor(dt, 32); dc += __shfl_xor(dc, 32);
      if (g == 0 && s < S) {
        const float nrm = sqrtf(sDq[s][nb]) * sqrtf(dc);
        const float sim = dt / fmaxf(nrm, EPSF) * sDelt[nb];
        const _Float16 h = (_Float16)sim;
        sim_hl[0][s][nb] = h;
        sim_hl[1][s][nb] = (_Float16)(sim - (float)h);
      }
    }
    pbuf ^= 1;
  }
  __syncthreads();

  // ================= tail: y = sim M^T ; G = sim y^T ; softmax + out ========
  for (int q = t; q < 1024; q += 256) {  // stage M
    const int hl = q >> 9, row = (q >> 3) & 63, c8 = (q & 7) * 8;
    const _Float16* wsM = reinterpret_cast<const _Float16*>(ws + 132);
    *reinterpret_cast<half8*>(&uA.M[hl][row][c8]) =
        *reinterpret_cast<const half8*>(wsM + hl * 4096 + row * 64 + c8);
  }
  __syncthreads();
  for (int tid = wid; tid < 12; tid += 4) {  // y-GEMM
    const int mt = tid >> 2, nt = tid & 3;
    f32x4 acc = zero4;
#pragma unroll
    for (int ks = 0; ks < 2; ++ks) {
      const int ko = ks * 32 + g * 8;
      int ar = mt * 16 + c; if (ar > 35) ar = 35;
      half8 a_h = *reinterpret_cast<const half8*>(&sim_hl[0][ar][ko]);
      half8 a_l = *reinterpret_cast<const half8*>(&sim_hl[1][ar][ko]);
      half8 b_h = *reinterpret_cast<const half8*>(&uA.M[0][nt * 16 + c][ko]);
      half8 b_l = *reinterpret_cast<const half8*>(&uA.M[1][nt * 16 + c][ko]);
      acc = mfma16(a_h, b_h, acc);
      acc = mfma16(a_h, b_l, acc);
      acc = mfma16(a_l, b_h, acc);
    }
#pragma unroll
    for (int r = 0; r < 4; ++r) {
      const int srow = mt * 16 + 4 * g + r;
      const int icol = nt * 16 + c;
      if (srow < S) {
        const float x = acc[r];
        const _Float16 h = (_Float16)x;
        uB.yhl[0][srow][icol] = h;
        uB.yhl[1][srow][icol] = (_Float16)(x - (float)h);
      }
    }
  }
  __syncthreads();
  for (int tid = wid; tid < 9; tid += 4) {  // G-GEMM
    const int mt = tid / 3, nt = tid % 3;
    f32x4 acc = zero4;
#pragma unroll
    for (int ks = 0; ks < 2; ++ks) {
      const int ko = ks * 32 + g * 8;
      int ar = mt * 16 + c; if (ar > 35) ar = 35;
      int br = nt * 16 + c; if (br > 35) br = 35;
      half8 a_h = *reinterpret_cast<const half8*>(&sim_hl[0][ar][ko]);
      half8 a_l = *reinterpret_cast<const half8*>(&sim_hl[1][ar][ko]);
      half8 b_h = *reinterpret_cast<const half8*>(&uB.yhl[0][br][ko]);
      half8 b_l = *reinterpret_cast<const half8*>(&uB.yhl[1][br][ko]);
      acc = mfma16(a_h, b_h, acc);
      acc = mfma16(a_h, b_l, acc);
      acc = mfma16(a_l, b_h, acc);
    }
#pragma unroll
    for (int r = 0; r < 4; ++r) {
      const int srow = mt * 16 + 4 * g + r;
      const int tcol = nt * 16 + c;
      if (srow < S) uA.t1.G[srow][tcol] = acc[r];
    }
  }
  __syncthreads();
  if (t < S) {  // p[t] = u . sim_t
    float a = 0.f;
#pragma unroll
    for (int n = 0; n < 64; ++n)
      a += ((float)sim_hl[0][t][n] + (float)sim_hl[1][t][n]) * sU[n];
    sP[t] = a;
  } else if (t >= 64 && t < 64 + S) {  // simcv[t] = cv . sim_t
    const int r = t - 64;
    float a = 0.f;
#pragma unroll
    for (int n = 0; n < 64; ++n)
      a += ((float)sim_hl[0][r][n] + (float)sim_hl[1][r][n]) * sCv[n];
    sScv[r] = a;
  }
  __syncthreads();
  if (t < S) {  // fused row-softmax(G + p) . simcv -> tanh
    float lg[36];
    float m = -1e30f;
#pragma unroll
    for (int t2 = 0; t2 < S; ++t2) {
      lg[t2] = uA.t1.G[t][t2] + sP[t2];
      m = fmaxf(m, lg[t2]);
    }
    float se = 0.f, sv = 0.f;
#pragma unroll
    for (int t2 = 0; t2 < S; ++t2) {
      float e = expf(lg[t2] - m);
      se += e; sv += e * sScv[t2];
    }
    sRed[t] = tanhf(sv / se + sBconst);
  }
  __syncthreads();
  if (t == 0) {
    float a = 0.f;
    for (int s = 0; s < S; ++s) a += sRed[s];
    out[ii * NC + ci] = a * (1.f / 36.f);
  }
}

// ---------------- fallback (R2 kernel, used when ws too small) ----------------
constexpr int ST1 = CH + 8;
constexpr int STT = 56;
constexpr int STI = 68;
constexpr int STC = 52;
constexpr int STH = 72;
constexpr int STA = 40;

__global__ __launch_bounds__(256, 2) void i2t_fb(
    const float* __restrict__ images, const float* __restrict__ captions,
    const float* __restrict__ delt, const float* __restrict__ ws,
    float* __restrict__ out) {
  __shared__ union {
    struct { _Float16 cap[2][32][ST1]; _Float16 img[2][48][ST1]; } s1;
    float lpart[4][32][36];
    struct { _Float16 capT[2][64][STT]; float img32[36][STI]; } s2;
    _Float16 M[2][64][STH];
    float G[36][52];
  } rA;
  __shared__ union {
    float La[32][37];
    float ctxT[64][STC];
    _Float16 yhl[2][48][STH];
  } rB;
  __shared__ _Float16 attn_hl[2][48][STA];
  __shared__ _Float16 sim_hl[2][48][STH];
  __shared__ float wrcp[32];
  __shared__ float sDelt[64], sCv[64], sU[64];
  __shared__ float sP[36], sScv[36], sRed[36];
  __shared__ float sBconst;

  const int t = threadIdx.x;
  const int lane = t & 63, wid = t >> 6;
  const int mrow = lane & 15, grp = lane >> 4;
  const int bid = blockIdx.x;
  const int xcd = bid & 7, l = bid >> 3;
  const int ci = (xcd >> 1) * 12 + (l % 12);
  const int ii = (xcd & 1) * 24 + (l / 12);
  const float* cap = captions + ci * (W * D);
  const float* img = images + ii * (S * D);
  const f32x4 zero4 = {0.f, 0.f, 0.f, 0.f};

  if (t < 64) { sDelt[t] = delt[t]; sCv[t] = ws[t]; sU[t] = ws[66 + t]; }
  if (t == 64) sBconst = ws[64];

  f32x4 acc1[2][3];
#pragma unroll
  for (int mt = 0; mt < 2; ++mt)
#pragma unroll
    for (int nt = 0; nt < 3; ++nt) acc1[mt][nt] = zero4;

  for (int ch = 0; ch < NCH; ++ch) {
    const int d0 = ch * CH;
    __syncthreads();
    for (int q = t; q < 1088; q += 256) {
      const int row = q >> 4, c4 = (q & 15) * 4;
      const float* src = (row < 32) ? (cap + row * D + d0 + c4)
                                    : (img + (row - 32) * D + d0 + c4);
      float4 v = *reinterpret_cast<const float4*>(src);
      half4 hh, ll;
      hh[0] = (_Float16)v.x; ll[0] = (_Float16)(v.x - (float)hh[0]);
      hh[1] = (_Float16)v.y; ll[1] = (_Float16)(v.y - (float)hh[1]);
      hh[2] = (_Float16)v.z; ll[2] = (_Float16)(v.z - (float)hh[2]);
      hh[3] = (_Float16)v.w; ll[3] = (_Float16)(v.w - (float)hh[3]);
      _Float16* dh = (row < 32) ? &rA.s1.cap[0][row][c4] : &rA.s1.img[0][row - 32][c4];
      _Float16* dl = (row < 32) ? &rA.s1.cap[1][row][c4] : &rA.s1.img[1][row - 32][c4];
      *reinterpret_cast<half4*>(dh) = hh;
      *reinterpret_cast<half4*>(dl) = ll;
    }
    __syncthreads();
    if ((ch & 3) == wid) {
#pragma unroll
      for (int ks = 0; ks < 2; ++ks) {
        const int ko = ks * 32 + grp * 8;
        half8 ah[2], al[2], bh[3], bl[3];
#pragma unroll
        for (int mt = 0; mt < 2; ++mt) {
          ah[mt] = *reinterpret_cast<const half8*>(&rA.s1.cap[0][mt * 16 + mrow][ko]);
          al[mt] = *reinterpret_cast<const half8*>(&rA.s1.cap[1][mt * 16 + mrow][ko]);
        }
#pragma unroll
        for (int nt = 0; nt < 3; ++nt) {
          bh[nt] = *reinterpret_cast<const half8*>(&rA.s1.img[0][nt * 16 + mrow][ko]);
          bl[nt] = *reinterpret_cast<const half8*>(&rA.s1.img[1][nt * 16 + mrow][ko]);
        }
#pragma unroll
        for (int mt = 0; mt < 2; ++mt)
#pragma unroll
          for (int nt = 0; nt < 3; ++nt) {
            acc1[mt][nt] = mfma16(ah[mt], bh[nt], acc1[mt][nt]);
            acc1[mt][nt] = mfma16(ah[mt], bl[nt], acc1[mt][nt]);
            acc1[mt][nt] = mfma16(al[mt], bh[nt], acc1[mt][nt]);
          }
      }
    }
  }
  __syncthreads();
#pragma unroll
  for (int mt = 0; mt < 2; ++mt)
#pragma unroll
    for (int nt = 0; nt < 3; ++nt)
#pragma unroll
      for (int r = 0; r < 4; ++r) {
        const int w = mt * 16 + grp * 4 + r;
        const int s = nt * 16 + mrow;
        if (s < S) rA.lpart[wid][w][s] = acc1[mt][nt][r];
      }
  __syncthreads();
  {
    const float* lp = &rA.lpart[0][0][0];
    for (int e = t; e < W * S; e += 256) {
      float x = lp[e] + lp[e + 1152] + lp[e + 2304] + lp[e + 3456];
      x = x > 0.f ? x : 0.1f * x;
      rB.La[e / S][e % S] = x;
    }
  }
  __syncthreads();
  if (t < W) {
    float sum = 0.f;
    for (int s = 0; s < S; ++s) { float v = rB.La[t][s]; sum += v * v; }
    wrcp[t] = 1.f / (sqrtf(sum) + EPSF);
  }
  __syncthreads();
  if (t < S) {
    float lw[32];
    float m = -1e30f;
#pragma unroll
    for (int w = 0; w < W; ++w) {
      float v = 9.f * rB.La[w][t] * wrcp[w];
      lw[w] = v;
      m = fmaxf(m, v);
    }
    float sum = 0.f;
#pragma unroll
    for (int w = 0; w < W; ++w) { lw[w] = expf(lw[w] - m); sum += lw[w]; }
    const float r = 1.f / sum;
#pragma unroll
    for (int w = 0; w < W; ++w) {
      float a = lw[w] * r;
      _Float16 h = (_Float16)a;
      attn_hl[0][t][w] = h;
      attn_hl[1][t][w] = (_Float16)(a - (float)h);
    }
  }
  __syncthreads();

  half8 a2h[3], a2l[3];
#pragma unroll
  for (int mt = 0; mt < 3; ++mt) {
    a2h[mt] = *reinterpret_cast<const half8*>(&attn_hl[0][mt * 16 + mrow][grp * 8]);
    a2l[mt] = *reinterpret_cast<const half8*>(&attn_hl[1][mt * 16 + mrow][grp * 8]);
  }
  for (int ch = 0; ch < NCH; ++ch) {
    const int d0 = ch * CH;
    __syncthreads();
    {
      const int dl = t & 63, wb = (t >> 6) * 8;
      half8 hh, ll;
#pragma unroll
      for (int k = 0; k < 8; ++k) {
        float x = cap[(wb + k) * D + d0 + dl];
        hh[k] = (_Float16)x;
        ll[k] = (_Float16)(x - (float)hh[k]);
      }
      *reinterpret_cast<half8*>(&rA.s2.capT[0][dl][wb]) = hh;
      *reinterpret_cast<half8*>(&rA.s2.capT[1][dl][wb]) = ll;
    }
    for (int q = t; q < 576; q += 256) {
      const int sr = q >> 4, c4 = (q & 15) * 4;
      float4 v = *reinterpret_cast<const float4*>(img + sr * D + d0 + c4);
      *reinterpret_cast<float4*>(&rA.s2.img32[sr][c4]) = v;
    }
    __syncthreads();
    {
      const int dloc = wid * 16 + mrow;
      half8 b_h = *reinterpret_cast<const half8*>(&rA.s2.capT[0][dloc][grp * 8]);
      half8 b_l = *reinterpret_cast<const half8*>(&rA.s2.capT[1][dloc][grp * 8]);
#pragma unroll
      for (int mt = 0; mt < 3; ++mt) {
        f32x4 acc = zero4;
        acc = mfma16(a2h[mt], b_h, acc);
        acc = mfma16(a2h[mt], b_l, acc);
        acc = mfma16(a2l[mt], b_h, acc);
        const int s0 = mt * 16 + grp * 4;
        if (s0 < S) *reinterpret_cast<f32x4*>(&rB.ctxT[dloc][s0]) = acc;
      }
    }
    __syncthreads();
    if (t < 144) {
      const int s = t % 36, nbl = t / 36;
      const int n = ch * 4 + nbl;
      float dt = 0.f, dc = 0.f, dq = 0.f;
#pragma unroll
      for (int j4 = 0; j4 < 4; ++j4) {
        f32x4 qv = *reinterpret_cast<const f32x4*>(&rA.s2.img32[s][nbl * 16 + j4 * 4]);
#pragma unroll
        for (int jj = 0; jj < 4; ++jj) {
          float cx = rB.ctxT[nbl * 16 + j4 * 4 + jj][s];
          float q = qv[jj];
          dt += q * cx; dc += cx * cx; dq += q * q;
        }
      }
      float sim = dt / fmaxf(sqrtf(dq) * sqrtf(dc), EPSF) * sDelt[n];
      _Float16 h = (_Float16)sim;
      sim_hl[0][s][n] = h;
      sim_hl[1][s][n] = (_Float16)(sim - (float)h);
    }
  }
  __syncthreads();

  for (int q = t; q < 1024; q += 256) {
    const int hl = q >> 9, row = (q >> 3) & 63, c8 = (q & 7) * 8;
    const _Float16* wsM = reinterpret_cast<const _Float16*>(ws + 132);
    *reinterpret_cast<half8*>(&rA.M[hl][row][c8]) =
        *reinterpret_cast<const half8*>(wsM + hl * 4096 + row * 64 + c8);
  }
  __syncthreads();
  for (int tid = wid; tid < 12; tid += 4) {
    const int mt = tid >> 2, nt = tid & 3;
    f32x4 acc = zero4;
#pragma unroll
    for (int ks = 0; ks < 2; ++ks) {
      const int ko = ks * 32 + grp * 8;
      half8 a_h = *reinterpret_cast<const half8*>(&sim_hl[0][mt * 16 + mrow][ko]);
      half8 a_l = *reinterpret_cast<const half8*>(&sim_hl[1][mt * 16 + mrow][ko]);
      half8 b_h = *reinterpret_cast<const half8*>(&rA.M[0][nt * 16 + mrow][ko]);
      half8 b_l = *reinterpret_cast<const half8*>(&rA.M[1][nt * 16 + mrow][ko]);
      acc = mfma16(a_h, b_h, acc);
      acc = mfma16(a_h, b_l, acc);
      acc = mfma16(a_l, b_h, acc);
    }
#pragma unroll
    for (int r = 0; r < 4; ++r) {
      const int srow = mt * 16 + grp * 4 + r;
      const int icol = nt * 16 + mrow;
      float x = acc[r];
      _Float16 h = (_Float16)x;
      rB.yhl[0][srow][icol] = h;
      rB.yhl[1][srow][icol] = (_Float16)(x - (float)h);
    }
  }
  __syncthreads();
  for (int tid = wid; tid < 9; tid += 4) {
    const int mt = tid / 3, nt = tid % 3;
    f32x4 acc = zero4;
#pragma unroll
    for (int ks = 0; ks < 2; ++ks) {
      const int ko = ks * 32 + grp * 8;
      half8 a_h = *reinterpret_cast<const half8*>(&sim_hl[0][mt * 16 + mrow][ko]);
      half8 a_l = *reinterpret_cast<const half8*>(&sim_hl[1][mt * 16 + mrow][ko]);
      half8 b_h = *reinterpret_cast<const half8*>(&rB.yhl[0][nt * 16 + mrow][ko]);
      half8 b_l = *reinterpret_cast<const half8*>(&rB.yhl[1][nt * 16 + mrow][ko]);
      acc = mfma16(a_h, b_h, acc);
      acc = mfma16(a_h, b_l, acc);
      acc = mfma16(a_l, b_h, acc);
    }
#pragma unroll
    for (int r = 0; r < 4; ++r) {
      const int srow = mt * 16 + grp * 4 + r;
      const int tcol = nt * 16 + mrow;
      if (srow < S) rA.G[srow][tcol] = acc[r];
    }
  }
  __syncthreads();
  if (t < S) {
    float a = 0.f;
#pragma unroll
    for (int n = 0; n < 64; ++n)
      a += ((float)sim_hl[0][t][n] + (float)sim_hl[1][t][n]) * sU[n];
    sP[t] = a;
  } else if (t >= 64 && t < 64 + S) {
    const int r = t - 64;
    float a = 0.f;
#pragma unroll
    for (int n = 0; n < 64; ++n)
      a += ((float)sim_hl[0][r][n] + (float)sim_hl[1][r][n]) * sCv[n];
    sScv[r] = a;
  }
  __syncthreads();
  if (t < S) {
    float lg[36];
    float m = -1e30f;
#pragma unroll
    for (int t2 = 0; t2 < S; ++t2) {
      lg[t2] = rA.G[t][t2] + sP[t2];
      m = fmaxf(m, lg[t2]);
    }
    float se = 0.f, sv = 0.f;
#pragma unroll
    for (int t2 = 0; t2 < S; ++t2) {
      float e = expf(lg[t2] - m);
      se += e; sv += e * sScv[t2];
    }
    sRed[t] = tanhf(sv / se + sBconst);
  }
  __syncthreads();
  if (t == 0) {
    float a = 0.f;
    for (int s = 0; s < S; ++s) a += sRed[s];
    out[ii * NC + ci] = a * (1.f / 36.f);
  }
}

extern "C" void kernel_launch(void* const* d_in, const int* in_sizes, int n_in,
                              void* d_out, int out_size, void* d_ws, size_t ws_size,
                              hipStream_t stream) {
  const float* images   = (const float*)d_in[0];
  const float* captions = (const float*)d_in[1];
  // d_in[2] = cap_lens (unused: reference uniformizes to full length)
  const float* delt  = (const float*)d_in[3];
  const float* W1    = (const float*)d_in[4];
  const float* b1    = (const float*)d_in[5];
  const float* W2    = (const float*)d_in[6];
  // d_in[7] = b2: cancels inside the row-softmax, unused
  const float* convW = (const float*)d_in[8];
  const float* convB = (const float*)d_in[9];
  const float* Wm    = (const float*)d_in[10];
  const float* bm    = (const float*)d_in[11];
  const float* V     = (const float*)d_in[12];
  const float* g     = (const float*)d_in[13];
  const float* bo    = (const float*)d_in[14];
  float* ws  = (float*)d_ws;
  float* out = (float*)d_out;

  prep_kernel<<<1, 256, 0, stream>>>(W1, b1, W2, convW, convB, Wm, bm, V, g, bo, ws);

  if (ws_size >= WS_NEED) {
    char* base = (char*)d_ws;
    _Float16* capH  = (_Float16*)(base + OFF_CAPH);
    _Float16* capL  = (_Float16*)(base + OFF_CAPL);
    _Float16* capTH = (_Float16*)(base + OFF_CAPTH);
    _Float16* capTL = (_Float16*)(base + OFF_CAPTL);
    _Float16* imgH  = (_Float16*)(base + OFF_IMGH);
    _Float16* imgL  = (_Float16*)(base + OFF_IMGL);
    float*    dq    = (float*)(base + OFF_DQ);
    conv_cap<<<dim3(NC, 16), 256, 0, stream>>>(captions, capH, capL, capTH, capTL);
    conv_img<<<dim3(NI, 16), 256, 0, stream>>>(images, imgH, imgL, dq);
    i2t_fast<<<dim3(NI * NC), 256, 0, stream>>>(images, capH, capL, capTH, capTL,
                                                imgH, imgL, dq, delt, ws, out);
  } else {
    i2t_fb<<<dim3(NI * NC), 256, 0, stream>>>(images, captions, delt, ws, out);
  }
}

// Round 4
// 203.688 us; speedup vs baseline: 3.0875x; 1.6928x over previous
//
#include <hip/hip_runtime.h>

#define EPSF 1e-8f

constexpr int NI = 48, NC = 48, S = 36, W = 32, D = 1024, NB = 64;
constexpr int CH = 64;            // k-chunk
constexpr int NCH = D / CH;       // 16

typedef _Float16 half8 __attribute__((ext_vector_type(8)));
typedef _Float16 half4 __attribute__((ext_vector_type(4)));
typedef float f32x4 __attribute__((ext_vector_type(4)));

__device__ __forceinline__ f32x4 mfma16(half8 a, half8 b, f32x4 c) {
  return __builtin_amdgcn_mfma_f32_16x16x32_f16(a, b, c, 0, 0, 0);
}

// ---- ws layout (bytes) ----
constexpr size_t OFF_CAPTH = 17408;                      // after prep floats
constexpr size_t SZ_CAPT   = (size_t)48 * 32 * 1024 * 2; // 3.14 MB
constexpr size_t OFF_CAPTL = OFF_CAPTH + SZ_CAPT;
constexpr size_t OFF_L     = OFF_CAPTL + SZ_CAPT;
constexpr size_t SZ_L      = (size_t)1536 * 1728 * 4;    // 10.6 MB
constexpr size_t WS_NEED   = OFF_L + SZ_L;               // ~16.9 MB

// ---------------- prep: fold conv/MeanOut/out-linear into cv[64], bconst;
// M = W1^T W2 (f16 hi/lo), u = W2^T b1 ----------------
__global__ __launch_bounds__(256) void prep_kernel(
    const float* __restrict__ W1, const float* __restrict__ b1,
    const float* __restrict__ W2,
    const float* __restrict__ convW, const float* __restrict__ convB,
    const float* __restrict__ Wm, const float* __restrict__ bm,
    const float* __restrict__ V, const float* __restrict__ g,
    const float* __restrict__ bo, float* __restrict__ ws) {
  __shared__ float sW1[64][68];
  __shared__ float sW2[64][68];
  __shared__ float wn[256];
  __shared__ float wv[64];
  __shared__ float vscale;
  const int t = threadIdx.x;
  for (int q = t; q < 2048; q += 256) {
    const int m = q >> 10, r = (q >> 4) & 63, c4 = (q & 15) * 4;
    const float* src = (m == 0 ? W1 : W2) + r * 64 + c4;
    float4 v = *reinterpret_cast<const float4*>(src);
    float* dst = (m == 0) ? &sW1[r][c4] : &sW2[r][c4];
    dst[0] = v.x; dst[1] = v.y; dst[2] = v.z; dst[3] = v.w;
  }
  if (t == 0) {
    float s = 0.f;
    for (int h = 0; h < 256; ++h) s += V[h] * V[h];
    vscale = g[0] / sqrtf(s);
  }
  __syncthreads();
  wn[t] = V[t] * vscale;
  __syncthreads();
  if (t < 64) {
    float acc = 0.f;
    for (int h = 0; h < 256; ++h)
      acc += 0.5f * (Wm[t * 512 + 2 * h] + Wm[t * 512 + 2 * h + 1]) * wn[h];
    wv[t] = acc;
  }
  __syncthreads();
  if (t < 64) {
    float acc = 0.f;
    for (int m = 0; m < 64; ++m) {
      float ce = 0.f;
      for (int k = 0; k < 8; ++k) ce += convW[k * 4096 + t * 64 + m];
      acc += 0.125f * ce * wv[m];
    }
    ws[t] = acc;  // cv
  }
  if (t == 0) {
    float bh = 0.f;
    for (int h = 0; h < 256; ++h) bh += 0.5f * (bm[2 * h] + bm[2 * h + 1]) * wn[h];
    float bc = 0.f;
    for (int m = 0; m < 64; ++m) bc += convB[m] * wv[m];
    ws[64] = bh + bc + bo[0];  // bconst
  }
  if (t < 64) {  // u = W2^T b1
    float a = 0.f;
    for (int k = 0; k < 64; ++k) a += b1[k] * sW2[k][t];
    ws[66 + t] = a;
  }
  // M = W1^T W2 -> f16 hi/lo at ws+132
  {
    const int i = t >> 2, j0 = (t & 3) * 16;
    float acc[16];
#pragma unroll
    for (int jj = 0; jj < 16; ++jj) acc[jj] = 0.f;
    for (int k = 0; k < 64; ++k) {
      const float w1v = sW1[k][i];
#pragma unroll
      for (int jj = 0; jj < 16; ++jj) acc[jj] += w1v * sW2[k][j0 + jj];
    }
    _Float16* wsM = reinterpret_cast<_Float16*>(ws + 132);
#pragma unroll
    for (int jj = 0; jj < 16; ++jj) {
      const float x = acc[jj];
      const _Float16 h = (_Float16)x;
      wsM[i * 64 + j0 + jj] = h;
      wsM[4096 + i * 64 + j0 + jj] = (_Float16)(x - (float)h);
    }
  }
}

// ---------------- convert captions: transposed f16 hi/lo ----------------
__global__ __launch_bounds__(256) void conv_cap(
    const float* __restrict__ cap, _Float16* __restrict__ capTH,
    _Float16* __restrict__ capTL) {
  __shared__ _Float16 tH[64][40], tL[64][40];
  const int t = threadIdx.x;
  const int c = blockIdx.x, ch = blockIdx.y;
  const int d0 = ch * 64;
  for (int q = t; q < 512; q += 256) {
    const int w = q >> 4, c4 = (q & 15) * 4;
    const size_t gi = ((size_t)c * 32 + w) * 1024 + d0 + c4;
    float4 v = *reinterpret_cast<const float4*>(cap + gi);
    half4 hh, ll;
    hh[0] = (_Float16)v.x; ll[0] = (_Float16)(v.x - (float)hh[0]);
    hh[1] = (_Float16)v.y; ll[1] = (_Float16)(v.y - (float)hh[1]);
    hh[2] = (_Float16)v.z; ll[2] = (_Float16)(v.z - (float)hh[2]);
    hh[3] = (_Float16)v.w; ll[3] = (_Float16)(v.w - (float)hh[3]);
#pragma unroll
    for (int j = 0; j < 4; ++j) { tH[c4 + j][w] = hh[j]; tL[c4 + j][w] = ll[j]; }
  }
  __syncthreads();
  for (int q = t; q < 512; q += 256) {
    const int hl = q >> 8, dd = (q >> 2) & 63, w8 = (q & 3) * 8;
    half8 v = *reinterpret_cast<const half8*>(hl ? &tL[dd][w8] : &tH[dd][w8]);
    _Float16* dst = (hl ? capTL : capTH) + ((size_t)c * 1024 + d0 + dd) * 32 + w8;
    *reinterpret_cast<half8*>(dst) = v;
  }
}

// ---------------- batched L-GEMM: L[(c,w)][(i,s)] = leaky(cap·img^T) ----------------
__global__ __launch_bounds__(256, 2) void gemmL(
    const float* __restrict__ captions, const float* __restrict__ images,
    float* __restrict__ L) {
  __shared__ _Float16 sA[2][96][72];
  __shared__ _Float16 sB[2][96][72];
  const int t = threadIdx.x;
  const int lane = t & 63, wid = t >> 6;
  const int c = lane & 15, g = lane >> 4;
  const int bm = blockIdx.x / 18, bn = blockIdx.x % 18;  // 16 x 18
  const int m0 = bm * 96, n0 = bn * 96;
  const int wm = wid >> 1, wn = wid & 1;

  f32x4 acc[3][3] = {};
  f32x4 pf[6][2];
  auto LD = [&](int ch) {
#pragma unroll
    for (int k = 0; k < 3; ++k) {
      const int u = t + k * 256;
      const int row = u >> 3, c8 = (u & 7) * 8;
      const float* src = captions + (size_t)(m0 + row) * 1024 + ch * 64 + c8;
      pf[k][0] = *reinterpret_cast<const f32x4*>(src);
      pf[k][1] = *reinterpret_cast<const f32x4*>(src + 4);
    }
#pragma unroll
    for (int k = 0; k < 3; ++k) {
      const int u = t + k * 256;
      const int row = u >> 3, c8 = (u & 7) * 8;
      const float* src = images + (size_t)(n0 + row) * 1024 + ch * 64 + c8;
      pf[3 + k][0] = *reinterpret_cast<const f32x4*>(src);
      pf[3 + k][1] = *reinterpret_cast<const f32x4*>(src + 4);
    }
  };
  auto ST = [&]() {
#pragma unroll
    for (int q = 0; q < 6; ++q) {
      const int u = t + (q % 3) * 256;
      const int row = u >> 3, c8 = (u & 7) * 8;
      half8 hh, ll;
#pragma unroll
      for (int j = 0; j < 8; ++j) {
        const float x = pf[q][j >> 2][j & 3];
        hh[j] = (_Float16)x;
        ll[j] = (_Float16)(x - (float)hh[j]);
      }
      _Float16* dh = (q < 3) ? &sA[0][row][c8] : &sB[0][row][c8];
      _Float16* dl = (q < 3) ? &sA[1][row][c8] : &sB[1][row][c8];
      *reinterpret_cast<half8*>(dh) = hh;
      *reinterpret_cast<half8*>(dl) = ll;
    }
  };
  LD(0);
  for (int ch = 0; ch < NCH; ++ch) {
    __syncthreads();
    ST();
    if (ch < NCH - 1) LD(ch + 1);
    __syncthreads();
#pragma unroll
    for (int ks = 0; ks < 2; ++ks) {
      const int ko = ks * 32 + g * 8;
      half8 ah[3], al[3], bh[3], bl[3];
#pragma unroll
      for (int mt = 0; mt < 3; ++mt) {
        ah[mt] = *reinterpret_cast<const half8*>(&sA[0][wm * 48 + mt * 16 + c][ko]);
        al[mt] = *reinterpret_cast<const half8*>(&sA[1][wm * 48 + mt * 16 + c][ko]);
      }
#pragma unroll
      for (int nt = 0; nt < 3; ++nt) {
        bh[nt] = *reinterpret_cast<const half8*>(&sB[0][wn * 48 + nt * 16 + c][ko]);
        bl[nt] = *reinterpret_cast<const half8*>(&sB[1][wn * 48 + nt * 16 + c][ko]);
      }
#pragma unroll
      for (int mt = 0; mt < 3; ++mt)
#pragma unroll
        for (int nt = 0; nt < 3; ++nt) {
          acc[mt][nt] = mfma16(ah[mt], bh[nt], acc[mt][nt]);
          acc[mt][nt] = mfma16(ah[mt], bl[nt], acc[mt][nt]);
          acc[mt][nt] = mfma16(al[mt], bh[nt], acc[mt][nt]);
        }
    }
  }
#pragma unroll
  for (int mt = 0; mt < 3; ++mt)
#pragma unroll
    for (int nt = 0; nt < 3; ++nt)
#pragma unroll
      for (int r = 0; r < 4; ++r) {
        const int m = m0 + wm * 48 + mt * 16 + 4 * g + r;
        const int n = n0 + wn * 48 + nt * 16 + c;
        float x = acc[mt][nt][r];
        x = x > 0.f ? x : 0.1f * x;            // leaky fused here
        L[(size_t)m * 1728 + n] = x;
      }
}

// swizzled byte offset within a 36x64-half row-major tile (row stride 128 B)
__device__ __forceinline__ int swz(int row, int nbyte) {
  return row * 128 + (nbyte ^ ((row & 7) << 4));
}

// ---------------- per-(caption, 2 images) kernel ----------------
__global__ __launch_bounds__(256, 3) void i2t_sim(
    const float* __restrict__ images,
    const _Float16* __restrict__ capTH, const _Float16* __restrict__ capTL,
    const float* __restrict__ L, const float* __restrict__ delt,
    const float* __restrict__ ws, float* __restrict__ out) {
  __shared__ union {
    _Float16 capT[2][2][2048];                            // [buf][hl] 16384 B
    float La2[2][32][40];                                  // 10240 B
    struct { _Float16 yhl[2][36 * 64]; float G[36][52]; } tl;  // 16704 B
  } U;
  __shared__ _Float16 attn[2][2][36][40];   // 11520 B
  __shared__ _Float16 simS[2][2][36 * 64];  // 18432 B (swizzled rows)
  __shared__ float wrcp2[2][32];
  __shared__ float sDelt[64], sCv[64], sU[64];
  __shared__ float sP[2][36], sScv[2][36], sRed[2][36];
  __shared__ float sBconst;

  const int t = threadIdx.x;
  const int lane = t & 63, wid = t >> 6;
  const int c = lane & 15, g = lane >> 4;
  const int bid = blockIdx.x;
  const int xcd = bid & 7, l = bid >> 3;              // l < 144
  const int ci = (xcd >> 1) * 12 + (l % 12);
  const int i0 = ((xcd & 1) * 12 + (l / 12)) * 2;     // images i0, i0+1

  if (t < 64) { sDelt[t] = delt[t]; sCv[t] = ws[t]; sU[t] = ws[66 + t]; }
  if (t == 64) sBconst = ws[64];

  // ---- chunk staging (capT only), double-buffered, reg-prefetched
  half8 rc[2];
  auto ldC = [&](int ch) {
#pragma unroll
    for (int k = 0; k < 2; ++k) {
      const int u = t + k * 256;
      const int hl = u >> 8, dd = (u >> 2) & 63, w8 = (u & 3) * 8;
      rc[k] = *reinterpret_cast<const half8*>(
          (hl ? capTL : capTH) + ((size_t)ci * 1024 + ch * 64 + dd) * 32 + w8);
    }
  };
  auto stC = [&](int buf) {
#pragma unroll
    for (int k = 0; k < 2; ++k) {
      const int u = t + k * 256;
      const int hl = u >> 8, dd = (u >> 2) & 63, w8 = (u & 3) * 8;
      char* base = (char*)&U.capT[buf][hl][0];
      *reinterpret_cast<half8*>(base + dd * 64 + ((w8 * 2) ^ ((dd & 3) << 4))) = rc[k];
    }
  };
  ldC(0);  // overlaps the attn phases below (registers only)

  // ---- phase 1: load L tile (already leaky'd)
#pragma unroll
  for (int k = 0; k < 3; ++k) {
    const int u = t + k * 256;
    if (u < 576) {
      const int im = u >= 288, v = u - im * 288;
      const int w = v / 9, q4 = (v % 9) * 4;
      f32x4 x = *reinterpret_cast<const f32x4*>(
          L + (size_t)(ci * 32 + w) * 1728 + (size_t)(i0 + im) * 36 + q4);
      *reinterpret_cast<f32x4*>(&U.La2[im][w][q4]) = x;
    }
  }
  __syncthreads();
  // ---- phase 2: 1/l2norm over regions per (img, word)
  if (t < 64) {
    const int im = t >> 5, w = t & 31;
    float s = 0.f;
    for (int ss = 0; ss < 36; ++ss) { const float v = U.La2[im][w][ss]; s += v * v; }
    wrcp2[im][w] = 1.f / (sqrtf(s) + EPSF);
  }
  __syncthreads();
  // ---- phase 3: softmax over words per (img, region)
  if (t < 72) {
    const int im = t / 36, s = t % 36;
    float lw[32];
    float m = -1e30f;
#pragma unroll
    for (int w = 0; w < 32; ++w) {
      const float v = 9.f * U.La2[im][w][s] * wrcp2[im][w];
      lw[w] = v;
      m = fmaxf(m, v);
    }
    float sum = 0.f;
#pragma unroll
    for (int w = 0; w < 32; ++w) { lw[w] = expf(lw[w] - m); sum += lw[w]; }
    const float r = 1.f / sum;
#pragma unroll
    for (int w = 0; w < 32; ++w) {
      const float a = lw[w] * r;
      const _Float16 h = (_Float16)a;
      attn[im][0][s][w] = h;
      attn[im][1][s][w] = (_Float16)(a - (float)h);
    }
  }
  __syncthreads();

  // ---- B-operand fragments (attn) and per-lane img pointers
  half8 b2h[2][3], b2l[2][3];
#pragma unroll
  for (int im = 0; im < 2; ++im)
#pragma unroll
    for (int mt = 0; mt < 3; ++mt) {
      int br = mt * 16 + c; if (br > 35) br = 35;
      b2h[im][mt] = *reinterpret_cast<const half8*>(&attn[im][0][br][g * 8]);
      b2l[im][mt] = *reinterpret_cast<const half8*>(&attn[im][1][br][g * 8]);
    }
  const float* pq[2][3];
#pragma unroll
  for (int im = 0; im < 2; ++im)
#pragma unroll
    for (int mt = 0; mt < 3; ++mt) {
      const int s = mt * 16 + c;
      const int sc = s < S ? s : 35;
      pq[im][mt] = images + ((size_t)(i0 + im) * 36 + sc) * 1024 + wid * 16 + 4 * g;
    }

  // ---- chunk loop: ctx via MFMA + in-register blockwise cosine
  for (int ch = 0; ch < NCH; ++ch) {
    const int buf = ch & 1;
    stC(buf);
    if (ch < NCH - 1) ldC(ch + 1);
    __syncthreads();
    // issue q loads early (L2-resident)
    f32x4 qv[2][3];
#pragma unroll
    for (int im = 0; im < 2; ++im)
#pragma unroll
      for (int mt = 0; mt < 3; ++mt)
        qv[im][mt] = *reinterpret_cast<const f32x4*>(pq[im][mt] + ch * 64);
    const int drow = wid * 16 + c;
    const int sw = (g * 16) ^ ((drow & 3) << 4);
    const char* c0b = (const char*)&U.capT[buf][0][0];
    const char* c1b = (const char*)&U.capT[buf][1][0];
    half8 Ah = *reinterpret_cast<const half8*>(c0b + drow * 64 + sw);
    half8 Al = *reinterpret_cast<const half8*>(c1b + drow * 64 + sw);
    const int nb = ch * 4 + wid;
#pragma unroll
    for (int im = 0; im < 2; ++im) {
#pragma unroll
      for (int mt = 0; mt < 3; ++mt) {
        f32x4 a = {0.f, 0.f, 0.f, 0.f};
        a = mfma16(Ah, b2h[im][mt], a);
        a = mfma16(Ah, b2l[im][mt], a);
        a = mfma16(Al, b2h[im][mt], a);
        // lane holds ctx[d = wid*16+4g+r][s = mt*16+c]
        const f32x4 q = qv[im][mt];
        float dt = a[0] * q[0] + a[1] * q[1] + a[2] * q[2] + a[3] * q[3];
        float dc = a[0] * a[0] + a[1] * a[1] + a[2] * a[2] + a[3] * a[3];
        float dq = q[0] * q[0] + q[1] * q[1] + q[2] * q[2] + q[3] * q[3];
        dt += __shfl_xor(dt, 16); dc += __shfl_xor(dc, 16); dq += __shfl_xor(dq, 16);
        dt += __shfl_xor(dt, 32); dc += __shfl_xor(dc, 32); dq += __shfl_xor(dq, 32);
        const int s = mt * 16 + c;
        if (g == 0 && s < S) {
          const float sm = dt / fmaxf(sqrtf(dq) * sqrtf(dc), EPSF) * sDelt[nb];
          const _Float16 h = (_Float16)sm;
          char* sb0 = (char*)&simS[im][0][0];
          char* sb1 = (char*)&simS[im][1][0];
          *reinterpret_cast<_Float16*>(sb0 + swz(s, nb * 2)) = h;
          *reinterpret_cast<_Float16*>(sb1 + swz(s, nb * 2)) = (_Float16)(sm - (float)h);
        }
      }
    }
    __syncthreads();
  }

  // ---- p[t2] = u·sim_t2 ; scv[t2] = cv·sim_t2 (both images)
  if (t < 72) {
    const int im = t / 36, s = t % 36;
    const char* sb0 = (const char*)&simS[im][0][0];
    const char* sb1 = (const char*)&simS[im][1][0];
    float a = 0.f, b = 0.f;
#pragma unroll
    for (int n = 0; n < 64; ++n) {
      const float sv = (float)*reinterpret_cast<const _Float16*>(sb0 + swz(s, n * 2)) +
                       (float)*reinterpret_cast<const _Float16*>(sb1 + swz(s, n * 2));
      a += sv * sU[n];
      b += sv * sCv[n];
    }
    sP[im][s] = a;
    sScv[im][s] = b;
  }
  __syncthreads();

  const _Float16* wsM = reinterpret_cast<const _Float16*>(ws + 132);
  for (int im = 0; im < 2; ++im) {
    const char* sb0 = (const char*)&simS[im][0][0];
    const char* sb1 = (const char*)&simS[im][1][0];
    // ---- y = sim·M^T (M from global, L2-hot)
    for (int tid = wid; tid < 12; tid += 4) {
      const int mt = tid >> 2, nt = tid & 3;
      f32x4 a = {0.f, 0.f, 0.f, 0.f};
#pragma unroll
      for (int ks = 0; ks < 2; ++ks) {
        const int ko = ks * 32 + g * 8;
        int ar = mt * 16 + c; if (ar > 35) ar = 35;
        half8 a_h = *reinterpret_cast<const half8*>(sb0 + swz(ar, ko * 2));
        half8 a_l = *reinterpret_cast<const half8*>(sb1 + swz(ar, ko * 2));
        half8 b_h = *reinterpret_cast<const half8*>(wsM + (nt * 16 + c) * 64 + ko);
        half8 b_l = *reinterpret_cast<const half8*>(wsM + 4096 + (nt * 16 + c) * 64 + ko);
        a = mfma16(a_h, b_h, a);
        a = mfma16(a_h, b_l, a);
        a = mfma16(a_l, b_h, a);
      }
#pragma unroll
      for (int r = 0; r < 4; ++r) {
        const int srow = mt * 16 + 4 * g + r;
        const int icol = nt * 16 + c;
        if (srow < S) {
          const float x = a[r];
          const _Float16 h = (_Float16)x;
          char* yb0 = (char*)&U.tl.yhl[0][0];
          char* yb1 = (char*)&U.tl.yhl[1][0];
          *reinterpret_cast<_Float16*>(yb0 + swz(srow, icol * 2)) = h;
          *reinterpret_cast<_Float16*>(yb1 + swz(srow, icol * 2)) = (_Float16)(x - (float)h);
        }
      }
    }
    __syncthreads();
    // ---- G = sim·y^T
    for (int tid = wid; tid < 9; tid += 4) {
      const int mt = tid / 3, nt = tid % 3;
      f32x4 a = {0.f, 0.f, 0.f, 0.f};
#pragma unroll
      for (int ks = 0; ks < 2; ++ks) {
        const int ko = ks * 32 + g * 8;
        int ar = mt * 16 + c; if (ar > 35) ar = 35;
        int br = nt * 16 + c; if (br > 35) br = 35;
        half8 a_h = *reinterpret_cast<const half8*>(sb0 + swz(ar, ko * 2));
        half8 a_l = *reinterpret_cast<const half8*>(sb1 + swz(ar, ko * 2));
        const char* yb0 = (const char*)&U.tl.yhl[0][0];
        const char* yb1 = (const char*)&U.tl.yhl[1][0];
        half8 b_h = *reinterpret_cast<const half8*>(yb0 + swz(br, ko * 2));
        half8 b_l = *reinterpret_cast<const half8*>(yb1 + swz(br, ko * 2));
        a = mfma16(a_h, b_h, a);
        a = mfma16(a_h, b_l, a);
        a = mfma16(a_l, b_h, a);
      }
#pragma unroll
      for (int r = 0; r < 4; ++r) {
        const int srow = mt * 16 + 4 * g + r;
        const int tcol = nt * 16 + c;
        if (srow < S) U.tl.G[srow][tcol] = a[r];
      }
    }
    __syncthreads();
    // ---- fused row-softmax(G + p) · scv -> tanh
    if (t < S) {
      float lg[36];
      float m = -1e30f;
#pragma unroll
      for (int t2 = 0; t2 < S; ++t2) {
        lg[t2] = U.tl.G[t][t2] + sP[im][t2];
        m = fmaxf(m, lg[t2]);
      }
      float se = 0.f, sv = 0.f;
#pragma unroll
      for (int t2 = 0; t2 < S; ++t2) {
        const float e = expf(lg[t2] - m);
        se += e; sv += e * sScv[im][t2];
      }
      sRed[im][t] = tanhf(sv / se + sBconst);
    }
    __syncthreads();
  }
  if (t < 2) {
    float a = 0.f;
    for (int s = 0; s < S; ++s) a += sRed[t][s];
    out[(size_t)(i0 + t) * NC + ci] = a * (1.f / 36.f);
  }
}

// ---------------- fallback (R2 kernel, used when ws too small) ----------------
constexpr int ST1 = CH + 8;
constexpr int STT = 56;
constexpr int STI = 68;
constexpr int STC = 52;
constexpr int STH = 72;
constexpr int STA = 40;

__global__ __launch_bounds__(256, 2) void i2t_fb(
    const float* __restrict__ images, const float* __restrict__ captions,
    const float* __restrict__ delt, const float* __restrict__ ws,
    float* __restrict__ out) {
  __shared__ union {
    struct { _Float16 cap[2][32][ST1]; _Float16 img[2][48][ST1]; } s1;
    float lpart[4][32][36];
    struct { _Float16 capT[2][64][STT]; float img32[36][STI]; } s2;
    _Float16 M[2][64][STH];
    float G[36][52];
  } rA;
  __shared__ union {
    float La[32][37];
    float ctxT[64][STC];
    _Float16 yhl[2][48][STH];
  } rB;
  __shared__ _Float16 attn_hl[2][48][STA];
  __shared__ _Float16 sim_hl[2][48][STH];
  __shared__ float wrcp[32];
  __shared__ float sDelt[64], sCv[64], sU[64];
  __shared__ float sP[36], sScv[36], sRed[36];
  __shared__ float sBconst;

  const int t = threadIdx.x;
  const int lane = t & 63, wid = t >> 6;
  const int mrow = lane & 15, grp = lane >> 4;
  const int bid = blockIdx.x;
  const int xcd = bid & 7, l = bid >> 3;
  const int ci = (xcd >> 1) * 12 + (l % 12);
  const int ii = (xcd & 1) * 24 + (l / 12);
  const float* cap = captions + ci * (W * D);
  const float* img = images + ii * (S * D);
  const f32x4 zero4 = {0.f, 0.f, 0.f, 0.f};

  if (t < 64) { sDelt[t] = delt[t]; sCv[t] = ws[t]; sU[t] = ws[66 + t]; }
  if (t == 64) sBconst = ws[64];

  f32x4 acc1[2][3];
#pragma unroll
  for (int mt = 0; mt < 2; ++mt)
#pragma unroll
    for (int nt = 0; nt < 3; ++nt) acc1[mt][nt] = zero4;

  for (int ch = 0; ch < NCH; ++ch) {
    const int d0 = ch * CH;
    __syncthreads();
    for (int q = t; q < 1088; q += 256) {
      const int row = q >> 4, c4 = (q & 15) * 4;
      const float* src = (row < 32) ? (cap + row * D + d0 + c4)
                                    : (img + (row - 32) * D + d0 + c4);
      float4 v = *reinterpret_cast<const float4*>(src);
      half4 hh, ll;
      hh[0] = (_Float16)v.x; ll[0] = (_Float16)(v.x - (float)hh[0]);
      hh[1] = (_Float16)v.y; ll[1] = (_Float16)(v.y - (float)hh[1]);
      hh[2] = (_Float16)v.z; ll[2] = (_Float16)(v.z - (float)hh[2]);
      hh[3] = (_Float16)v.w; ll[3] = (_Float16)(v.w - (float)hh[3]);
      _Float16* dh = (row < 32) ? &rA.s1.cap[0][row][c4] : &rA.s1.img[0][row - 32][c4];
      _Float16* dl = (row < 32) ? &rA.s1.cap[1][row][c4] : &rA.s1.img[1][row - 32][c4];
      *reinterpret_cast<half4*>(dh) = hh;
      *reinterpret_cast<half4*>(dl) = ll;
    }
    __syncthreads();
    if ((ch & 3) == wid) {
#pragma unroll
      for (int ks = 0; ks < 2; ++ks) {
        const int ko = ks * 32 + grp * 8;
        half8 ah[2], al[2], bh[3], bl[3];
#pragma unroll
        for (int mt = 0; mt < 2; ++mt) {
          ah[mt] = *reinterpret_cast<const half8*>(&rA.s1.cap[0][mt * 16 + mrow][ko]);
          al[mt] = *reinterpret_cast<const half8*>(&rA.s1.cap[1][mt * 16 + mrow][ko]);
        }
#pragma unroll
        for (int nt = 0; nt < 3; ++nt) {
          bh[nt] = *reinterpret_cast<const half8*>(&rA.s1.img[0][nt * 16 + mrow][ko]);
          bl[nt] = *reinterpret_cast<const half8*>(&rA.s1.img[1][nt * 16 + mrow][ko]);
        }
#pragma unroll
        for (int mt = 0; mt < 2; ++mt)
#pragma unroll
          for (int nt = 0; nt < 3; ++nt) {
            acc1[mt][nt] = mfma16(ah[mt], bh[nt], acc1[mt][nt]);
            acc1[mt][nt] = mfma16(ah[mt], bl[nt], acc1[mt][nt]);
            acc1[mt][nt] = mfma16(al[mt], bh[nt], acc1[mt][nt]);
          }
      }
    }
  }
  __syncthreads();
#pragma unroll
  for (int mt = 0; mt < 2; ++mt)
#pragma unroll
    for (int nt = 0; nt < 3; ++nt)
#pragma unroll
      for (int r = 0; r < 4; ++r) {
        const int w = mt * 16 + grp * 4 + r;
        const int s = nt * 16 + mrow;
        if (s < S) rA.lpart[wid][w][s] = acc1[mt][nt][r];
      }
  __syncthreads();
  {
    const float* lp = &rA.lpart[0][0][0];
    for (int e = t; e < W * S; e += 256) {
      float x = lp[e] + lp[e + 1152] + lp[e + 2304] + lp[e + 3456];
      x = x > 0.f ? x : 0.1f * x;
      rB.La[e / S][e % S] = x;
    }
  }
  __syncthreads();
  if (t < W) {
    float sum = 0.f;
    for (int s = 0; s < S; ++s) { float v = rB.La[t][s]; sum += v * v; }
    wrcp[t] = 1.f / (sqrtf(sum) + EPSF);
  }
  __syncthreads();
  if (t < S) {
    float lw[32];
    float m = -1e30f;
#pragma unroll
    for (int w = 0; w < W; ++w) {
      float v = 9.f * rB.La[w][t] * wrcp[w];
      lw[w] = v;
      m = fmaxf(m, v);
    }
    float sum = 0.f;
#pragma unroll
    for (int w = 0; w < W; ++w) { lw[w] = expf(lw[w] - m); sum += lw[w]; }
    const float r = 1.f / sum;
#pragma unroll
    for (int w = 0; w < W; ++w) {
      float a = lw[w] * r;
      _Float16 h = (_Float16)a;
      attn_hl[0][t][w] = h;
      attn_hl[1][t][w] = (_Float16)(a - (float)h);
    }
  }
  __syncthreads();

  half8 a2h[3], a2l[3];
#pragma unroll
  for (int mt = 0; mt < 3; ++mt) {
    a2h[mt] = *reinterpret_cast<const half8*>(&attn_hl[0][mt * 16 + mrow][grp * 8]);
    a2l[mt] = *reinterpret_cast<const half8*>(&attn_hl[1][mt * 16 + mrow][grp * 8]);
  }
  for (int ch = 0; ch < NCH; ++ch) {
    const int d0 = ch * CH;
    __syncthreads();
    {
      const int dl = t & 63, wb = (t >> 6) * 8;
      half8 hh, ll;
#pragma unroll
      for (int k = 0; k < 8; ++k) {
        float x = cap[(wb + k) * D + d0 + dl];
        hh[k] = (_Float16)x;
        ll[k] = (_Float16)(x - (float)hh[k]);
      }
      *reinterpret_cast<half8*>(&rA.s2.capT[0][dl][wb]) = hh;
      *reinterpret_cast<half8*>(&rA.s2.capT[1][dl][wb]) = ll;
    }
    for (int q = t; q < 576; q += 256) {
      const int sr = q >> 4, c4 = (q & 15) * 4;
      float4 v = *reinterpret_cast<const float4*>(img + sr * D + d0 + c4);
      *reinterpret_cast<float4*>(&rA.s2.img32[sr][c4]) = v;
    }
    __syncthreads();
    {
      const int dloc = wid * 16 + mrow;
      half8 b_h = *reinterpret_cast<const half8*>(&rA.s2.capT[0][dloc][grp * 8]);
      half8 b_l = *reinterpret_cast<const half8*>(&rA.s2.capT[1][dloc][grp * 8]);
#pragma unroll
      for (int mt = 0; mt < 3; ++mt) {
        f32x4 acc = zero4;
        acc = mfma16(a2h[mt], b_h, acc);
        acc = mfma16(a2h[mt], b_l, acc);
        acc = mfma16(a2l[mt], b_h, acc);
        const int s0 = mt * 16 + grp * 4;
        if (s0 < S) *reinterpret_cast<f32x4*>(&rB.ctxT[dloc][s0]) = acc;
      }
    }
    __syncthreads();
    if (t < 144) {
      const int s = t % 36, nbl = t / 36;
      const int n = ch * 4 + nbl;
      float dt = 0.f, dc = 0.f, dq = 0.f;
#pragma unroll
      for (int j4 = 0; j4 < 4; ++j4) {
        f32x4 qv = *reinterpret_cast<const f32x4*>(&rA.s2.img32[s][nbl * 16 + j4 * 4]);
#pragma unroll
        for (int jj = 0; jj < 4; ++jj) {
          float cx = rB.ctxT[nbl * 16 + j4 * 4 + jj][s];
          float q = qv[jj];
          dt += q * cx; dc += cx * cx; dq += q * q;
        }
      }
      float sim = dt / fmaxf(sqrtf(dq) * sqrtf(dc), EPSF) * sDelt[n];
      _Float16 h = (_Float16)sim;
      sim_hl[0][s][n] = h;
      sim_hl[1][s][n] = (_Float16)(sim - (float)h);
    }
  }
  __syncthreads();

  for (int q = t; q < 1024; q += 256) {
    const int hl = q >> 9, row = (q >> 3) & 63, c8 = (q & 7) * 8;
    const _Float16* wsM = reinterpret_cast<const _Float16*>(ws + 132);
    *reinterpret_cast<half8*>(&rA.M[hl][row][c8]) =
        *reinterpret_cast<const half8*>(wsM + hl * 4096 + row * 64 + c8);
  }
  __syncthreads();
  for (int tid = wid; tid < 12; tid += 4) {
    const int mt = tid >> 2, nt = tid & 3;
    f32x4 acc = zero4;
#pragma unroll
    for (int ks = 0; ks < 2; ++ks) {
      const int ko = ks * 32 + grp * 8;
      half8 a_h = *reinterpret_cast<const half8*>(&sim_hl[0][mt * 16 + mrow][ko]);
      half8 a_l = *reinterpret_cast<const half8*>(&sim_hl[1][mt * 16 + mrow][ko]);
      half8 b_h = *reinterpret_cast<const half8*>(&rA.M[0][nt * 16 + mrow][ko]);
      half8 b_l = *reinterpret_cast<const half8*>(&rA.M[1][nt * 16 + mrow][ko]);
      acc = mfma16(a_h, b_h, acc);
      acc = mfma16(a_h, b_l, acc);
      acc = mfma16(a_l, b_h, acc);
    }
#pragma unroll
    for (int r = 0; r < 4; ++r) {
      const int srow = mt * 16 + grp * 4 + r;
      const int icol = nt * 16 + mrow;
      float x = acc[r];
      _Float16 h = (_Float16)x;
      rB.yhl[0][srow][icol] = h;
      rB.yhl[1][srow][icol] = (_Float16)(x - (float)h);
    }
  }
  __syncthreads();
  for (int tid = wid; tid < 9; tid += 4) {
    const int mt = tid / 3, nt = tid % 3;
    f32x4 acc = zero4;
#pragma unroll
    for (int ks = 0; ks < 2; ++ks) {
      const int ko = ks * 32 + grp * 8;
      half8 a_h = *reinterpret_cast<const half8*>(&sim_hl[0][mt * 16 + mrow][ko]);
      half8 a_l = *reinterpret_cast<const half8*>(&sim_hl[1][mt * 16 + mrow][ko]);
      half8 b_h = *reinterpret_cast<const half8*>(&rB.yhl[0][nt * 16 + mrow][ko]);
      half8 b_l = *reinterpret_cast<const half8*>(&rB.yhl[1][nt * 16 + mrow][ko]);
      acc = mfma16(a_h, b_h, acc);
      acc = mfma16(a_h, b_l, acc);
      acc = mfma16(a_l, b_h, acc);
    }
#pragma unroll
    for (int r = 0; r < 4; ++r) {
      const int srow = mt * 16 + grp * 4 + r;
      const int tcol = nt * 16 + mrow;
      if (srow < S) rA.G[srow][tcol] = acc[r];
    }
  }
  __syncthreads();
  if (t < S) {
    float a = 0.f;
#pragma unroll
    for (int n = 0; n < 64; ++n)
      a += ((float)sim_hl[0][t][n] + (float)sim_hl[1][t][n]) * sU[n];
    sP[t] = a;
  } else if (t >= 64 && t < 64 + S) {
    const int r = t - 64;
    float a = 0.f;
#pragma unroll
    for (int n = 0; n < 64; ++n)
      a += ((float)sim_hl[0][r][n] + (float)sim_hl[1][r][n]) * sCv[n];
    sScv[r] = a;
  }
  __syncthreads();
  if (t < S) {
    float lg[36];
    float m = -1e30f;
#pragma unroll
    for (int t2 = 0; t2 < S; ++t2) {
      lg[t2] = rA.G[t][t2] + sP[t2];
      m = fmaxf(m, lg[t2]);
    }
    float se = 0.f, sv = 0.f;
#pragma unroll
    for (int t2 = 0; t2 < S; ++t2) {
      float e = expf(lg[t2] - m);
      se += e; sv += e * sScv[t2];
    }
    sRed[t] = tanhf(sv / se + sBconst);
  }
  __syncthreads();
  if (t == 0) {
    float a = 0.f;
    for (int s = 0; s < S; ++s) a += sRed[s];
    out[ii * NC + ci] = a * (1.f / 36.f);
  }
}

extern "C" void kernel_launch(void* const* d_in, const int* in_sizes, int n_in,
                              void* d_out, int out_size, void* d_ws, size_t ws_size,
                              hipStream_t stream) {
  const float* images   = (const float*)d_in[0];
  const float* captions = (const float*)d_in[1];
  // d_in[2] = cap_lens (unused: reference uniformizes to full length)
  const float* delt  = (const float*)d_in[3];
  const float* W1    = (const float*)d_in[4];
  const float* b1    = (const float*)d_in[5];
  const float* W2    = (const float*)d_in[6];
  // d_in[7] = b2: cancels inside the row-softmax, unused
  const float* convW = (const float*)d_in[8];
  const float* convB = (const float*)d_in[9];
  const float* Wm    = (const float*)d_in[10];
  const float* bm    = (const float*)d_in[11];
  const float* V     = (const float*)d_in[12];
  const float* g     = (const float*)d_in[13];
  const float* bo    = (const float*)d_in[14];
  float* ws  = (float*)d_ws;
  float* out = (float*)d_out;

  prep_kernel<<<1, 256, 0, stream>>>(W1, b1, W2, convW, convB, Wm, bm, V, g, bo, ws);

  if (ws_size >= WS_NEED) {
    char* base = (char*)d_ws;
    _Float16* capTH = (_Float16*)(base + OFF_CAPTH);
    _Float16* capTL = (_Float16*)(base + OFF_CAPTL);
    float*    Lbuf  = (float*)(base + OFF_L);
    conv_cap<<<dim3(NC, 16), 256, 0, stream>>>(captions, capTH, capTL);
    gemmL<<<dim3(288), 256, 0, stream>>>(captions, images, Lbuf);
    i2t_sim<<<dim3(1152), 256, 0, stream>>>(images, capTH, capTL, Lbuf, delt, ws, out);
  } else {
    i2t_fb<<<dim3(NI * NC), 256, 0, stream>>>(images, captions, delt, ws, out);
  }
}